// Round 7
// baseline (1589.454 us; speedup 1.0000x reference)
//
#include <hip/hip_runtime.h>
#include <hip/hip_bf16.h>

// GraphEncoder: NNConv (edge-MLP 16->256->1024->1024 + einsum + scatter) + 3x GINConv.
// R14: 1537us. gemm256p 125.5us = 750 TF, MfmaUtil 29.6. Address folding changed
// NOTHING -> VALUBusy tracks MfmaUtil-2 in every run (gfx94x-fallback counter
// double-counts MFMA as VALU); the VALU-storm theory was a ghost. 3 schedule
// variants all ~750 TF: per-phase serial LDS+MFMA model caps ~40-50%, observed 30%.
// Stop grinding the schedule. Budget: GEMM ~940us, ~600us in 55 small dispatches.
// R15: (1) gemm256msg = enn-L3 GEMM + fused einsum/scatter epilogue (kills wec
// write+read 184MB/chunk and all 5 nnconv_msg dispatches; LDS msg[256][64] reduce,
// 4 wn-passes, then 1 atomicAdd/(e,o)/block). CE: 4608 -> 2560 B/edge -> 3 chunks.
// (2) 16 cvt -> 1 batched kernel; 11 transposes -> 1; memset(nbr) folded into elu.

#define NN 50000
#define EE 200000

typedef unsigned short u16;
typedef __attribute__((ext_vector_type(8))) short frag8;
typedef __attribute__((ext_vector_type(4))) float f32x4;

__device__ __forceinline__ float bf2f(u16 u) {
    union { unsigned int i; float f; } v; v.i = ((unsigned int)u) << 16; return v.f;
}
__device__ __forceinline__ u16 f2bf(float f) {
    union { float f; unsigned int i; } v; v.f = f;
    return (u16)((v.i + 0x7fffu + ((v.i >> 16) & 1u)) >> 16);
}
__device__ __forceinline__ float eluf(float v) {
    return v > 0.f ? v : __expf(v) - 1.f;
}

// ---------------- float dtype probe: fp32-as-bf16 shows crazy exponents ----------------
__global__ void probe_f32(const u16* __restrict__ raw, int* __restrict__ cnt) {
    int t = threadIdx.x;  // single block of 256
    int c = 0;
    for (int j = t; j < 1024; j += 256) {
        unsigned e = (raw[j] >> 7) & 0xFF;
        if (e >= 0xBF) c++;   // |v| >= 2^64: never in genuine N(0,1)-ish bf16 data
    }
    if (c) atomicAdd(cnt, c);
}

// ---------------- batched bf16 normalize: 16 tensors in one launch ----------------
struct CvtPtrs { const void* src[16]; u16* dst[16]; };
__global__ void cvt_all(CvtPtrs p, const int* __restrict__ cnt) {
    constexpr long L[16] = {800000, 3200000, 4096, 256, 262144, 1024, 1048576, 1024,
                            1024, 64, 49152, 768, 196608, 768, 49152, 192};
    long idx = (long)blockIdx.x * 256 + threadIdx.x;
    const bool isf32 = (*cnt >= 8);
    long base = 0;
    #pragma unroll
    for (int i = 0; i < 16; ++i) {
        if (idx >= base && idx < base + L[i]) {
            long k = idx - base;
            p.dst[i][k] = isf32 ? f2bf(((const float*)p.src[i])[k])
                                : ((const u16*)p.src[i])[k];
        }
        base += L[i];
    }
}

// ---------------- edge_index layout probe + conversion ----------------
__global__ void detect_idx64(const unsigned long long* __restrict__ p, int* __restrict__ flag) {
    long t = (long)blockIdx.x * 256 + threadIdx.x;
    if (t < EE) {
        unsigned long long v = p[t];
        if (v >> 31) atomicOr(flag, 1);   // int32-packed pairs have high bits set
    }
}
__global__ void convert_idx(const void* __restrict__ raw, const int* __restrict__ flag,
                            int* __restrict__ s_out, int* __restrict__ d_out) {
    long t = (long)blockIdx.x * 256 + threadIdx.x;
    if (t >= EE) return;
    if (*flag) {  // int32 layout
        const int* q = (const int*)raw;
        s_out[t] = q[t];
        d_out[t] = q[EE + t];
    } else {      // int64 layout
        const long long* q = (const long long*)raw;
        s_out[t] = (int)q[t];
        d_out[t] = (int)q[EE + t];
    }
}

// ---------------- batched bf16 transpose: 11 jobs [K,N]->[N,K] in one launch ----------
struct TransPtrs { const u16* in[11]; u16* out[11]; };
__global__ void transpose_all(TransPtrs p) {
    constexpr int TK[11] = {256, 1024, 64, 256, 256, 64, 256, 256, 64, 256, 256};
    constexpr int TN[11] = {1024, 1024, 256, 256, 64, 256, 256, 64, 256, 256, 64};
    long idx = (long)blockIdx.x * 256 + threadIdx.x;
    long base = 0;
    #pragma unroll
    for (int i = 0; i < 11; ++i) {
        const long sz = (long)TK[i] * TN[i];
        if (idx >= base && idx < base + sz) {
            long v = idx - base;
            int k = (int)(v / TN[i]);
            int n = (int)(v % TN[i]);
            p.out[i][(long)n * TK[i] + k] = p.in[i][v];
        }
        base += sz;
    }
}

// ---------------- edge MLP layer 1: h1 = ELU(attr @ W1 + b1), K=16, N=256 ----------------
__global__ void edge_mlp1(const u16* __restrict__ attr, const u16* __restrict__ w1,
                          const u16* __restrict__ b1, u16* __restrict__ h1, int ce) {
    __shared__ u16 sa[256];
    const int t = threadIdx.x;
    const int e0 = blockIdx.x * 16;
    const int cnt = min(16, ce - e0);
    sa[t] = (t < cnt * 16) ? attr[(long)e0 * 16 + t] : (u16)0;
    float w[16];
    #pragma unroll
    for (int i = 0; i < 16; ++i) w[i] = bf2f(w1[i * 256 + t]);
    const float bb = bf2f(b1[t]);
    __syncthreads();
    for (int e = 0; e < cnt; ++e) {
        float v = bb;
        #pragma unroll
        for (int i = 0; i < 16; ++i) v += bf2f(sa[e * 16 + i]) * w[i];
        h1[(long)(e0 + e) * 256 + t] = f2bf(eluf(v));
    }
}

// ---- stage 128x32 bf16 tile via global_load_lds (128^2 path, GIN g1) ----
__device__ __forceinline__ void stage_tile(const u16* g, long row_base, long max_row,
                                           int kstride, int k0, u16* s, int t) {
    int wave = t >> 6;
    #pragma unroll
    for (int j = 0; j < 2; ++j) {
        int c = t + 256 * j;                 // chunk id 0..511 (16B each)
        long r = row_base + (c >> 2);        // 4 chunks per 32-elem row
        if (r > max_row) r = max_row;        // tail clamp (masked at C store)
        const u16* gp = g + r * (long)kstride + k0 + (c & 3) * 8;
        __builtin_amdgcn_global_load_lds(
            (__attribute__((address_space(1))) void*)(void*)gp,
            (__attribute__((address_space(3))) void*)((char*)s + wave * 1024 + j * 4096),
            16, 0, 0);                       // HW writes LDS at base + lane*16
    }
}

// C = ELU(A[M,K] @ BT[N,K]^T + bias), bf16 out. N mult of 128, K mult of 32.
// XCD-swizzled 1D grid. Kept for GIN g1 (K=64).
__global__ __launch_bounds__(256)
void gemm_bt_bias_elu(const u16* __restrict__ A, const u16* __restrict__ BT,
                      const u16* __restrict__ bias, u16* __restrict__ C,
                      int M, int K, int N, int mpx, int lognt) {
    const int bid = blockIdx.x;
    const int xcd = bid & 7;
    const int j = bid >> 3;
    const int m_idx = xcd * mpx + (j >> lognt);
    const int n_idx = j & ((1 << lognt) - 1);
    const int num_m = (M + 127) >> 7;
    if (m_idx >= num_m) return;              // block-uniform; before any barrier

    __shared__ __align__(16) u16 sA[128 * 32];
    __shared__ __align__(16) u16 sB[128 * 32];
    const int t = threadIdx.x;
    const int lane = t & 63;
    const int wave = t >> 6;
    const int wr = wave >> 1, wc = wave & 1;
    const int quad = lane >> 4, l16 = lane & 15;
    const long m0 = (long)m_idx * 128;
    const int n0 = n_idx * 128;

    f32x4 acc[4][4];
    const f32x4 z4 = {0.f, 0.f, 0.f, 0.f};
    #pragma unroll
    for (int mi = 0; mi < 4; ++mi)
        #pragma unroll
        for (int ni = 0; ni < 4; ++ni)
            acc[mi][ni] = z4;

    for (int k0 = 0; k0 < K; k0 += 32) {
        stage_tile(A, m0, (long)M - 1, K, k0, sA, t);
        stage_tile(BT, n0, (long)N - 1, K, k0, sB, t);
        __syncthreads();
        frag8 af[4], bfv[4];
        #pragma unroll
        for (int mi = 0; mi < 4; ++mi)
            af[mi] = *(const frag8*)(sA + (wr * 64 + mi * 16 + l16) * 32 + quad * 8);
        #pragma unroll
        for (int ni = 0; ni < 4; ++ni)
            bfv[ni] = *(const frag8*)(sB + (wc * 64 + ni * 16 + l16) * 32 + quad * 8);
        #pragma unroll
        for (int mi = 0; mi < 4; ++mi)
            #pragma unroll
            for (int ni = 0; ni < 4; ++ni)
                acc[mi][ni] = __builtin_amdgcn_mfma_f32_16x16x32_bf16(af[mi], bfv[ni], acc[mi][ni], 0, 0, 0);
        __syncthreads();
    }

    #pragma unroll
    for (int mi = 0; mi < 4; ++mi) {
        #pragma unroll
        for (int r = 0; r < 4; ++r) {
            long row = m0 + wr * 64 + mi * 16 + quad * 4 + r;  // C/D: row = quad*4+reg
            if (row < M) {
                #pragma unroll
                for (int ni = 0; ni < 4; ++ni) {
                    int col = n0 + wc * 64 + ni * 16 + l16;    // C/D: col = lane&15
                    float v = acc[mi][ni][r] + bf2f(bias[col]);
                    C[row * (long)N + col] = f2bf(eluf(v));
                }
            }
        }
    }
}

// ---------------- 8-phase 256x256 GEMM core (R14 schedule, unchanged) ----------------
// LDS 128KB = buf{0,1} x {A0,A1,B0,B1} x 16KB; region = 128 rows x 64 k, row=128B,
// swizzle LDS[row][s] = global slot s^(row&7), separable -> folded base pointers.
// Phase: {reads; stage 1 region; [vmcnt(4) @ph4/8]; barrier; setprio; 16 MFMA;
// setprio; barrier}. Ledger in R12-R14 comments (verified passing).

#define QPHASE(PA0, PA1, PB0, PB1, QM, QN, LDA, LDB, VMW, STREG, SG, SRB, SRM, SCL, SKT) \
  do {                                                                           \
    if (LDA) {                                                                   \
      _Pragma("unroll")                                                          \
      for (int mi = 0; mi < 4; ++mi) {                                           \
        av[mi][0] = *(const frag8*)((PA0) + ((QM) * 4 + mi) * 2048);             \
        av[mi][1] = *(const frag8*)((PA1) + ((QM) * 4 + mi) * 2048);             \
      }                                                                          \
    }                                                                            \
    if ((LDB) >= 0) {                                                            \
      _Pragma("unroll")                                                          \
      for (int ni = 0; ni < 2; ++ni) {                                           \
        bv[(LDB) & 1][ni][0] = *(const frag8*)((PB0) + (((LDB) & 1) * 2 + ni) * 2048); \
        bv[(LDB) & 1][ni][1] = *(const frag8*)((PB1) + (((LDB) & 1) * 2 + ni) * 2048); \
      }                                                                          \
    }                                                                            \
    stage((STREG), (SG), (SRB), (SRM), (SKT), (SCL));                            \
    if (VMW) asm volatile("s_waitcnt vmcnt(4)" ::: "memory");                    \
    __builtin_amdgcn_s_barrier();                                                \
    __builtin_amdgcn_s_setprio(1);                                               \
    _Pragma("unroll")                                                            \
    for (int kk = 0; kk < 2; ++kk) {                                             \
      _Pragma("unroll")                                                          \
      for (int mi = 0; mi < 4; ++mi) {                                           \
        _Pragma("unroll")                                                        \
        for (int ni = 0; ni < 2; ++ni) {                                         \
          acc[(QM) * 4 + mi][(QN) * 2 + ni] =                                    \
              __builtin_amdgcn_mfma_f32_16x16x32_bf16(                           \
                  av[mi][kk], bv[(QN)][ni][kk],                                  \
                  acc[(QM) * 4 + mi][(QN) * 2 + ni], 0, 0, 0);                   \
        }                                                                        \
      }                                                                          \
    }                                                                            \
    __builtin_amdgcn_s_setprio(0);                                               \
    __builtin_amdgcn_s_barrier();                                                \
  } while (0)

// Shared body: computes acc for this block's 256x256 tile. Emitted via macro so
// gemm256p and gemm256msg share the verified K-loop exactly.
#define GEMM256_CORE()                                                                     \
    __shared__ __align__(16) u16 lds[2][4][8192];                                          \
    const int t = threadIdx.x;                                                             \
    const int lane = t & 63;                                                               \
    const int wave = t >> 6;                                                               \
    const int wm = wave >> 2;                                                              \
    const int wn = wave & 3;                                                               \
    const int quad = lane >> 4, l16 = lane & 15;                                           \
    const long m0 = (long)m_idx * 256;                                                     \
    const long n0 = (long)n_idx * 256;                                                     \
    const int aoff0 = l16 * 128 + ((quad ^ (l16 & 3)) << 4) + (((l16 >> 2) & 1) << 6);     \
    const int aoff1 = aoff0 ^ 64;                                                          \
    const int bex = (wn & 1) * 8192;                                                       \
    const char* pAX0 = (const char*)&lds[0][wm][0] + aoff0;                                \
    const char* pAX1 = (const char*)&lds[0][wm][0] + aoff1;                                \
    const char* pAY0 = (const char*)&lds[1][wm][0] + aoff0;                                \
    const char* pAY1 = (const char*)&lds[1][wm][0] + aoff1;                                \
    const char* pBX0 = (const char*)&lds[0][2 + (wn >> 1)][0] + aoff0 + bex;               \
    const char* pBX1 = (const char*)&lds[0][2 + (wn >> 1)][0] + aoff1 + bex;               \
    const char* pBY0 = (const char*)&lds[1][2 + (wn >> 1)][0] + aoff0 + bex;               \
    const char* pBY1 = (const char*)&lds[1][2 + (wn >> 1)][0] + aoff1 + bex;               \
    const int gslot = (((lane & 7) ^ ((lane >> 3) & 7)) << 3);                             \
    const int lane_row = lane >> 3;                                                        \
    const long lane_go = (long)lane_row * K + gslot;                                       \
    auto stage = [&](u16* sreg, const u16* G, long rbase, long rmax, int kt, bool cl) {    \
        _Pragma("unroll")                                                                  \
        for (int jj = 0; jj < 2; ++jj) {                                                   \
            const int ck = wave * 2 + jj;                                                  \
            const u16* gp;                                                                 \
            if (!cl) {                                                                     \
                gp = G + (rbase + ck * 8) * (long)K + ((long)kt << 6) + lane_go;           \
            } else {                                                                       \
                long r = rbase + ck * 8 + lane_row;                                        \
                if (r > rmax) r = rmax;                                                    \
                gp = G + r * (long)K + ((long)kt << 6) + gslot;                            \
            }                                                                              \
            __builtin_amdgcn_global_load_lds(                                              \
                (__attribute__((address_space(1))) void*)(void*)gp,                        \
                (__attribute__((address_space(3))) void*)((char*)sreg + ck * 1024),        \
                16, 0, 0);                                                                 \
        }                                                                                  \
    };                                                                                     \
    f32x4 acc[8][4];                                                                       \
    const f32x4 z4 = {0.f, 0.f, 0.f, 0.f};                                                 \
    _Pragma("unroll")                                                                      \
    for (int mi = 0; mi < 8; ++mi)                                                         \
        _Pragma("unroll")                                                                  \
        for (int ni = 0; ni < 4; ++ni)                                                     \
            acc[mi][ni] = z4;                                                              \
    frag8 av[4][2];                                                                        \
    frag8 bv[2][2][2];                                                                     \
    const int ntk = K >> 6;                                                                \
    const int niter = ntk >> 1;                                                            \
    const long MM = (long)M - 1, NMX = (long)N - 1;                                        \
    const bool aclamp = (m0 + 255) > MM;                                                   \
    stage(&lds[0][2][0], BT, n0,       NMX, 0, false);                                     \
    stage(&lds[0][3][0], BT, n0 + 128, NMX, 0, false);                                     \
    stage(&lds[0][0][0], A,  m0,       MM,  0, aclamp);                                    \
    stage(&lds[0][1][0], A,  m0 + 128, MM,  0, aclamp);                                    \
    stage(&lds[1][2][0], BT, n0,       NMX, 1, false);                                     \
    stage(&lds[1][3][0], BT, n0 + 128, NMX, 1, false);                                     \
    asm volatile("s_waitcnt vmcnt(4)" ::: "memory");                                       \
    __builtin_amdgcn_s_barrier();                                                          \
    for (int it = 0; it < niter; ++it) {                                                   \
        const int t1k = 2 * it + 1;                                                        \
        int t2k = 2 * it + 2; if (t2k > ntk - 1) t2k = ntk - 1;                            \
        int t3k = 2 * it + 3; if (t3k > ntk - 1) t3k = ntk - 1;                            \
        QPHASE(pAX0, pAX1, pBX0, pBX1, 0, 0, 1,  0, 0, &lds[1][0][0], A,  m0,       MM,  aclamp, t1k); \
        QPHASE(pAX0, pAX1, pBX0, pBX1, 0, 1, 0,  1, 0, &lds[1][1][0], A,  m0 + 128, MM,  aclamp, t1k); \
        QPHASE(pAX0, pAX1, pBX0, pBX1, 1, 0, 1, -1, 0, &lds[0][2][0], BT, n0,       NMX, false,  t2k); \
        QPHASE(pAX0, pAX1, pBX0, pBX1, 1, 1, 0, -1, 1, &lds[0][3][0], BT, n0 + 128, NMX, false,  t2k); \
        QPHASE(pAY0, pAY1, pBY0, pBY1, 0, 0, 1,  0, 0, &lds[0][0][0], A,  m0,       MM,  aclamp, t2k); \
        QPHASE(pAY0, pAY1, pBY0, pBY1, 0, 1, 0,  1, 0, &lds[0][1][0], A,  m0 + 128, MM,  aclamp, t2k); \
        QPHASE(pAY0, pAY1, pBY0, pBY1, 1, 0, 1, -1, 0, &lds[1][2][0], BT, n0,       NMX, false,  t3k); \
        QPHASE(pAY0, pAY1, pBY0, pBY1, 1, 1, 0, -1, 1, &lds[1][3][0], BT, n0 + 128, NMX, false,  t3k); \
    }                                                                                      \
    asm volatile("s_waitcnt vmcnt(0)" ::: "memory");

// Standard variant: C = ELU(acc + bias), bf16 out (enn-L2, GIN g2).
__global__ __launch_bounds__(512, 2)
void gemm256p(const u16* __restrict__ A, const u16* __restrict__ BT,
              const u16* __restrict__ bias, u16* __restrict__ C,
              int M, int K, int N, int mpx, int lognt) {
    const int bid = blockIdx.x;
    const int xcd = bid & 7;
    const int j = bid >> 3;
    const int m_idx = xcd * mpx + (j >> lognt);
    const int n_idx = j & ((1 << lognt) - 1);
    const int num_m = (M + 255) >> 8;
    if (m_idx >= num_m) return;              // block-uniform; before any barrier

    GEMM256_CORE()

    #pragma unroll
    for (int mi = 0; mi < 8; ++mi) {
        #pragma unroll
        for (int r = 0; r < 4; ++r) {
            long row = m0 + wm * 128 + mi * 16 + quad * 4 + r;   // C/D: row = quad*4+reg
            if (row < M) {
                #pragma unroll
                for (int ni = 0; ni < 4; ++ni) {
                    long col = n0 + wn * 64 + ni * 16 + l16;     // C/D: col = lane&15
                    float v = acc[mi][ni][r] + bf2f(bias[col]);
                    C[row * (long)N + col] = f2bf(eluf(v));
                }
            }
        }
    }
}

// Fused variant (enn-L3): we = ELU(acc + bias) consumed in-register; per-block
// partial msg[e,o] = sum_{i in block} we[e, i*64+o] * x[src[e], i] reduced in LDS
// (4 wn-passes, disjoint (row,o) ownership per pass), then atomicAdd into agg.
// wec tensor never materialized. Rows >= M masked (staged dup rows are garbage).
__global__ __launch_bounds__(512, 2)
void gemm256msg(const u16* __restrict__ A, const u16* __restrict__ BT,
                const u16* __restrict__ bias,
                const u16* __restrict__ xc, const int* __restrict__ srcp,
                const int* __restrict__ dstp, float* __restrict__ agg,
                int M, int K, int N, int mpx, int lognt) {
    const int bid = blockIdx.x;
    const int xcd = bid & 7;
    const int j = bid >> 3;
    const int m_idx = xcd * mpx + (j >> lognt);
    const int n_idx = j & ((1 << lognt) - 1);
    const int num_m = (M + 255) >> 8;
    if (m_idx >= num_m) return;              // block-uniform; before any barrier

    GEMM256_CORE()

    // ---- fused message epilogue ----
    __syncthreads();                          // all waves' stages drained; LDS reusable
    float* msgS = (float*)&lds[0][0][0];      // [256][64] f32 = 64KB
    float* sX   = (float*)((char*)&lds[0][0][0] + 65536);          // [256][4]
    int*   sDst = (int*)((char*)&lds[0][0][0] + 65536 + 4096);     // [256]
    const int ib4 = n_idx * 4;                // i base for this block's 4 i-values

    for (int v = t; v < 16384; v += 512) msgS[v] = 0.f;
    if (t < 256) {
        long e = m0 + t;
        long ec = (e <= MM) ? e : MM;         // clamp for safe loads
        int s = srcp[ec];
        sDst[t] = dstp[ec];
        #pragma unroll
        for (int jj = 0; jj < 4; ++jj)
            sX[t * 4 + jj] = bf2f(xc[(long)s * 16 + ib4 + jj]);
    }
    __syncthreads();

    for (int p = 0; p < 4; ++p) {             // wn-passes: disjoint (row,o) per pass
        if (wn == p) {
            #pragma unroll
            for (int mi = 0; mi < 8; ++mi) {
                #pragma unroll
                for (int r = 0; r < 4; ++r) {
                    int row = wm * 128 + mi * 16 + quad * 4 + r;
                    float xv = sX[row * 4 + wn];
                    #pragma unroll
                    for (int ni = 0; ni < 4; ++ni) {
                        int o = ni * 16 + l16;
                        float we = eluf(acc[mi][ni][r] + bf2f(bias[n0 + wn * 64 + o]));
                        msgS[row * 64 + o] += we * xv;
                    }
                }
            }
        }
        __syncthreads();
    }

    for (int v = t; v < 16384; v += 512) {
        int row = v >> 6, o = v & 63;
        long e = m0 + row;
        if (e < M) atomicAdd(&agg[(long)sDst[row] * 64 + o], msgS[v]);
    }
}

// C[M,64] fp32 = A[M,K] @ BT[64,K]^T + bias (no ELU). M-tile 256, N=64, K mult of 32.
__global__ __launch_bounds__(256)
void gemm_bt_f32(const u16* __restrict__ A, const u16* __restrict__ BT,
                 const u16* __restrict__ bias, float* __restrict__ C,
                 int M, int K) {
    __shared__ __align__(16) u16 sA[256 * 32];
    __shared__ __align__(16) u16 sB[64 * 32];
    const int t = threadIdx.x;
    const int lane = t & 63;
    const int wave = t >> 6;
    const int quad = lane >> 4, l16 = lane & 15;
    const long m0 = (long)blockIdx.x * 256;

    f32x4 acc[4][4];
    const f32x4 z4 = {0.f, 0.f, 0.f, 0.f};
    #pragma unroll
    for (int mi = 0; mi < 4; ++mi)
        #pragma unroll
        for (int ni = 0; ni < 4; ++ni)
            acc[mi][ni] = z4;

    for (int k0 = 0; k0 < K; k0 += 32) {
        #pragma unroll
        for (int j = 0; j < 4; ++j) {
            int c = t + 256 * j;
            long r = m0 + (c >> 2);
            if (r > (long)M - 1) r = (long)M - 1;
            const u16* gp = A + r * (long)K + k0 + (c & 3) * 8;
            __builtin_amdgcn_global_load_lds(
                (__attribute__((address_space(1))) void*)(void*)gp,
                (__attribute__((address_space(3))) void*)((char*)sA + wave * 1024 + j * 4096),
                16, 0, 0);
        }
        {
            int c = t;
            const u16* gp = BT + (long)(c >> 2) * K + k0 + (c & 3) * 8;
            __builtin_amdgcn_global_load_lds(
                (__attribute__((address_space(1))) void*)(void*)gp,
                (__attribute__((address_space(3))) void*)((char*)sB + wave * 1024),
                16, 0, 0);
        }
        __syncthreads();
        frag8 af[4], bfv[4];
        #pragma unroll
        for (int mi = 0; mi < 4; ++mi)
            af[mi] = *(const frag8*)(sA + (wave * 64 + mi * 16 + l16) * 32 + quad * 8);
        #pragma unroll
        for (int ni = 0; ni < 4; ++ni)
            bfv[ni] = *(const frag8*)(sB + (ni * 16 + l16) * 32 + quad * 8);
        #pragma unroll
        for (int mi = 0; mi < 4; ++mi)
            #pragma unroll
            for (int ni = 0; ni < 4; ++ni)
                acc[mi][ni] = __builtin_amdgcn_mfma_f32_16x16x32_bf16(af[mi], bfv[ni], acc[mi][ni], 0, 0, 0);
        __syncthreads();
    }

    #pragma unroll
    for (int mi = 0; mi < 4; ++mi) {
        #pragma unroll
        for (int r = 0; r < 4; ++r) {
            long row = m0 + wave * 64 + mi * 16 + quad * 4 + r;
            if (row < M) {
                #pragma unroll
                for (int ni = 0; ni < 4; ++ni) {
                    int col = ni * 16 + l16;
                    C[row * 64 + col] = acc[mi][ni][r] + bf2f(bias[col]);
                }
            }
        }
    }
}

// ---- x_cur(emb0) = x @ root_w + root_b + agg (in-place on agg) ----
__global__ void add_root(const u16* __restrict__ x, const u16* __restrict__ rw,
                         const u16* __restrict__ rb, float* __restrict__ xcur) {
    long idx = (long)blockIdx.x * 256 + threadIdx.x;
    if (idx >= (long)NN * 64) return;
    int d = (int)(idx & 63);
    long n = idx >> 6;
    float v = bf2f(rb[d]);
    #pragma unroll
    for (int i = 0; i < 16; ++i)
        v += bf2f(x[n * 16 + i]) * bf2f(rw[i * 64 + d]);
    xcur[idx] += v;
}

// elu to bf16 AND zero the nbr accumulator (same index space; kills a memset launch)
__global__ void elu_zero(const float* __restrict__ in, u16* __restrict__ o,
                         float* __restrict__ nbr, long n) {
    long idx = (long)blockIdx.x * 256 + threadIdx.x;
    if (idx < n) { o[idx] = f2bf(eluf(in[idx])); nbr[idx] = 0.f; }
}

__global__ void gin_scatter(const u16* __restrict__ xin, const int* __restrict__ src,
                            const int* __restrict__ dst, float* __restrict__ nbr) {
    long idx = (long)blockIdx.x * 256 + threadIdx.x;
    if (idx >= (long)EE * 64) return;
    int d = (int)(idx & 63);
    long e = idx >> 6;
    atomicAdd(&nbr[(long)dst[e] * 64 + d], bf2f(xin[(long)src[e] * 64 + d]));
}

__global__ void gin_combine(const u16* __restrict__ xin, const float* __restrict__ nbr,
                            u16* __restrict__ hin, long n) {
    long idx = (long)blockIdx.x * 256 + threadIdx.x;
    if (idx < n) hin[idx] = f2bf(bf2f(xin[idx]) + nbr[idx]);
}

// out[n,d,l] = emb_l[n*64+d] -- one float4 per (n,d), fully coalesced
__global__ void write_out(const float* __restrict__ e0, const float* __restrict__ e1,
                          const float* __restrict__ e2, const float* __restrict__ e3,
                          float* __restrict__ out) {
    long idx = (long)blockIdx.x * 256 + threadIdx.x;
    if (idx >= (long)NN * 64) return;
    float4 v = {e0[idx], e1[idx], e2[idx], e3[idx]};
    *(float4*)(out + idx * 4) = v;
}

extern "C" void kernel_launch(void* const* d_in, const int* in_sizes, int n_in,
                              void* d_out, int out_size, void* d_ws, size_t ws_size,
                              hipStream_t stream) {
    (void)in_sizes; (void)n_in; (void)out_size;
    const void* eidx = d_in[1];
    float* out = (float*)d_out;   // reference output dtype = float32

    char* ws = (char*)d_ws;
    size_t off = 0;
    auto alloc = [&](size_t bytes) {
        char* p = ws + off;
        off += (bytes + 255) & ~(size_t)255;
        return p;
    };
    // ---- persistent ----
    int* src32 = (int*)alloc((size_t)EE * 4);
    int* dst32 = (int*)alloc((size_t)EE * 4);
    int* flag  = (int*)alloc(256);
    int* cnt   = (int*)alloc(256);
    const int cv_idx[16] = {0, 2, 3, 4, 5, 6, 7, 8, 9, 10, 11, 12, 13, 14, 15, 16};
    const long cv_n[16]  = {800000, 3200000, 4096, 256, 262144, 1024, 1048576, 1024,
                            1024, 64, 49152, 768, 196608, 768, 49152, 192};
    u16* cv[16];
    for (int i = 0; i < 16; ++i) cv[i] = (u16*)alloc((size_t)cv_n[i] * 2);
    u16 *xc = cv[0], *eac = cv[1], *w1c = cv[2], *b1c = cv[3], *w2c = cv[4], *b2c = cv[5],
        *w3c = cv[6], *b3c = cv[7], *rwc = cv[8], *rbc = cv[9],
        *g1c = cv[10], *gb1c = cv[11], *g2c = cv[12], *gb2c = cv[13], *g3c = cv[14], *gb3c = cv[15];
    u16* w2t = (u16*)alloc((size_t)1024 * 256 * 2);
    u16* w3t = (u16*)alloc((size_t)1024 * 1024 * 2);
    u16* g1t = (u16*)alloc((size_t)3 * 256 * 64 * 2);
    u16* g2t = (u16*)alloc((size_t)3 * 256 * 256 * 2);
    u16* g3t = (u16*)alloc((size_t)3 * 64 * 256 * 2);
    // per-layer node embeddings, fp32 [N,64]; emb[0] doubles as agg/x_cur
    float* emb[4];
    for (int l = 0; l < 4; ++l) emb[l] = (float*)alloc((size_t)NN * 64 * 4);
    float* agg = emb[0];
    char* scratch = (char*)alloc(0);
    size_t avail = (ws_size > off + 4096) ? (ws_size - off - 4096) : 0;

    // ---- NNConv edge-chunk: h1c (512 B/e) + h2c (2048 B/e); wec eliminated ----
    long CE = (long)(avail / 2560) & ~255L;
    if (CE < 256) CE = 256;
    if (CE > 200192) CE = 200192;
    u16* h1c = (u16*)scratch;
    u16* h2c = (u16*)(scratch + (size_t)CE * 512);

    // ---- GIN node-chunk: nbr+xin fixed (19.2MB) + 1152 B/node ----
    long gin_fixed = (long)NN * 64 * 4 + (long)NN * 64 * 2;
    long gin_avail = (long)avail - gin_fixed;
    if (gin_avail < 0) gin_avail = 0;
    long CN = (gin_avail / 1152) & ~255L;
    if (CN < 256) CN = 256;
    if (CN > 50176) CN = 50176;
    float* nbr = (float*)scratch;
    u16* xin   = (u16*)(scratch + (size_t)NN * 64 * 4);
    u16* hin   = (u16*)(scratch + gin_fixed);
    u16* hg1   = hin + (size_t)CN * 64;
    u16* hg2   = hg1 + (size_t)CN * 256;

    auto cdiv = [](long a, long b) { return (unsigned)((a + b - 1) / b); };

    // dtype probe on x, then normalize all float inputs to bf16 (ONE batched launch)
    hipMemsetAsync(cnt, 0, 4, stream);
    probe_f32<<<1, 256, 0, stream>>>((const u16*)d_in[0], cnt);
    {
        CvtPtrs cp;
        for (int i = 0; i < 16; ++i) { cp.src[i] = d_in[cv_idx[i]]; cp.dst[i] = cv[i]; }
        long total = 0;
        for (int i = 0; i < 16; ++i) total += cv_n[i];
        cvt_all<<<cdiv(total, 256), 256, 0, stream>>>(cp, cnt);
    }

    // edge_index conversion (layout-robust)
    hipMemsetAsync(flag, 0, 4, stream);
    detect_idx64<<<cdiv(EE, 256), 256, 0, stream>>>((const unsigned long long*)eidx, flag);
    convert_idx<<<cdiv(EE, 256), 256, 0, stream>>>(eidx, flag, src32, dst32);

    // weight transposes [K,N] -> [N,K] (ONE batched launch; order matches TK/TN tables)
    {
        TransPtrs tp;
        tp.in[0] = w2c;  tp.out[0] = w2t;
        tp.in[1] = w3c;  tp.out[1] = w3t;
        for (int l = 0; l < 3; ++l) {
            tp.in[2 + 3 * l] = g1c + l * 64 * 256;   tp.out[2 + 3 * l] = g1t + l * 256 * 64;
            tp.in[3 + 3 * l] = g2c + l * 256 * 256;  tp.out[3 + 3 * l] = g2t + l * 256 * 256;
            tp.in[4 + 3 * l] = g3c + l * 256 * 64;   tp.out[4 + 3 * l] = g3t + l * 64 * 256;
        }
        long total = 262144 + 1048576 + 3 * (16384 + 65536 + 16384);
        transpose_all<<<cdiv(total, 256), 256, 0, stream>>>(tp);
    }

    // ---- NNConv (edge-chunked, einsum+scatter fused into L3 GEMM) ----
    hipMemsetAsync(agg, 0, (size_t)NN * 64 * 4, stream);
    for (long e0 = 0; e0 < EE; e0 += CE) {
        int ce = (int)((EE - e0 < CE) ? (EE - e0) : CE);
        int mpx2 = cdiv(cdiv(ce, 256), 8);
        edge_mlp1<<<cdiv(ce, 16), 256, 0, stream>>>(eac + e0 * 16, w1c, b1c, h1c, ce);
        gemm256p<<<8 * mpx2 * 4, 512, 0, stream>>>(h1c, w2t, b2c, h2c, ce, 256, 1024, mpx2, 2);
        gemm256msg<<<8 * mpx2 * 4, 512, 0, stream>>>(h2c, w3t, b3c, xc, src32 + e0, dst32 + e0,
                                                     agg, ce, 1024, 1024, mpx2, 2);
    }
    add_root<<<cdiv((long)NN * 64, 256), 256, 0, stream>>>(xc, rwc, rbc, agg);

    // ---- 3x GINConv (node-chunked MLP) ----
    for (int l = 0; l < 3; ++l) {
        elu_zero<<<cdiv((long)NN * 64, 256), 256, 0, stream>>>(emb[l], xin, nbr, (long)NN * 64);
        gin_scatter<<<cdiv((long)EE * 64, 256), 256, 0, stream>>>(xin, src32, dst32, nbr);
        for (long n0 = 0; n0 < NN; n0 += CN) {
            int cn = (int)((NN - n0 < CN) ? (NN - n0) : CN);
            int mpx = cdiv(cdiv(cn, 128), 8);
            int mpx2 = cdiv(cdiv(cn, 256), 8);
            gin_combine<<<cdiv((long)cn * 64, 256), 256, 0, stream>>>(xin + n0 * 64, nbr + n0 * 64, hin, (long)cn * 64);
            gemm_bt_bias_elu<<<8 * mpx * 2, 256, 0, stream>>>(hin, g1t + l * 256 * 64, gb1c + l * 256, hg1, cn, 64, 256, mpx, 1);
            gemm256p<<<8 * mpx2 * 1, 512, 0, stream>>>(hg1, g2t + l * 256 * 256, gb2c + l * 256, hg2, cn, 256, 256, mpx2, 0);
            gemm_bt_f32<<<cdiv(cn, 256), 256, 0, stream>>>(hg2, g3t + l * 64 * 256, gb3c + l * 64, emb[l + 1] + n0 * 64, cn, 256);
        }
    }
    write_out<<<cdiv((long)NN * 64, 256), 256, 0, stream>>>(emb[0], emb[1], emb[2], emb[3], out);
}

// Round 8
// 1529.714 us; speedup vs baseline: 1.0391x; 1.0391x over previous
//
#include <hip/hip_runtime.h>
#include <hip/hip_bf16.h>

// GraphEncoder: NNConv (edge-MLP 16->256->1024->1024 + einsum + scatter) + 3x GINConv.
// R15: 1589us. Fusion FAILED: gemm256msg 303us (+78/dispatch epilogue): 4x atomic
// traffic (51M vs 12.8M: each n-block holds only 4/16 i-values), 5M LDS RMW
// conflicts, 1 block/CU hides nothing. FETCH 68->131MB. Revert.
// Ledger: best total = R13 1509us; all 1-blk/CU GEMM schedules plateau 730-760 TF
// (LDS-read-throughput cap ~40% for this structure); stop schedule surgery.
// R16: (1) revert to separate nnconv_msg + R13 GIN config (g2 on 128^2 kernel);
// (2) keep R14 folded gemm256p (125us verified) + R15 batched cvt/transpose +
// elu_zero; (3) MFMA-ize edge-MLP L1: zero-pad attr to K=32 (once, persistent)
// + padded w1^T -> gemm_bt_bias_elu K=32 replaces scalar edge_mlp1.

#define NN 50000
#define EE 200000

typedef unsigned short u16;
typedef __attribute__((ext_vector_type(8))) short frag8;
typedef __attribute__((ext_vector_type(4))) float f32x4;

__device__ __forceinline__ float bf2f(u16 u) {
    union { unsigned int i; float f; } v; v.i = ((unsigned int)u) << 16; return v.f;
}
__device__ __forceinline__ u16 f2bf(float f) {
    union { float f; unsigned int i; } v; v.f = f;
    return (u16)((v.i + 0x7fffu + ((v.i >> 16) & 1u)) >> 16);
}
__device__ __forceinline__ float eluf(float v) {
    return v > 0.f ? v : __expf(v) - 1.f;
}

// ---------------- float dtype probe: fp32-as-bf16 shows crazy exponents ----------------
__global__ void probe_f32(const u16* __restrict__ raw, int* __restrict__ cnt) {
    int t = threadIdx.x;  // single block of 256
    int c = 0;
    for (int j = t; j < 1024; j += 256) {
        unsigned e = (raw[j] >> 7) & 0xFF;
        if (e >= 0xBF) c++;   // |v| >= 2^64: never in genuine N(0,1)-ish bf16 data
    }
    if (c) atomicAdd(cnt, c);
}

// ---------------- batched bf16 normalize: 16 tensors in one launch ----------------
struct CvtPtrs { const void* src[16]; u16* dst[16]; };
__global__ void cvt_all(CvtPtrs p, const int* __restrict__ cnt) {
    constexpr long L[16] = {800000, 3200000, 4096, 256, 262144, 1024, 1048576, 1024,
                            1024, 64, 49152, 768, 196608, 768, 49152, 192};
    long idx = (long)blockIdx.x * 256 + threadIdx.x;
    const bool isf32 = (*cnt >= 8);
    long base = 0;
    #pragma unroll
    for (int i = 0; i < 16; ++i) {
        if (idx >= base && idx < base + L[i]) {
            long k = idx - base;
            p.dst[i][k] = isf32 ? f2bf(((const float*)p.src[i])[k])
                                : ((const u16*)p.src[i])[k];
        }
        base += L[i];
    }
}

// ---------------- edge_index layout probe + conversion ----------------
__global__ void detect_idx64(const unsigned long long* __restrict__ p, int* __restrict__ flag) {
    long t = (long)blockIdx.x * 256 + threadIdx.x;
    if (t < EE) {
        unsigned long long v = p[t];
        if (v >> 31) atomicOr(flag, 1);   // int32-packed pairs have high bits set
    }
}
__global__ void convert_idx(const void* __restrict__ raw, const int* __restrict__ flag,
                            int* __restrict__ s_out, int* __restrict__ d_out) {
    long t = (long)blockIdx.x * 256 + threadIdx.x;
    if (t >= EE) return;
    if (*flag) {  // int32 layout
        const int* q = (const int*)raw;
        s_out[t] = q[t];
        d_out[t] = q[EE + t];
    } else {      // int64 layout
        const long long* q = (const long long*)raw;
        s_out[t] = (int)q[t];
        d_out[t] = (int)q[EE + t];
    }
}

// ---------------- batched bf16 transpose: 11 jobs [K,N]->[N,K] in one launch ----------
struct TransPtrs { const u16* in[11]; u16* out[11]; };
__global__ void transpose_all(TransPtrs p) {
    constexpr int TK[11] = {256, 1024, 64, 256, 256, 64, 256, 256, 64, 256, 256};
    constexpr int TN[11] = {1024, 1024, 256, 256, 64, 256, 256, 64, 256, 256, 64};
    long idx = (long)blockIdx.x * 256 + threadIdx.x;
    long base = 0;
    #pragma unroll
    for (int i = 0; i < 11; ++i) {
        const long sz = (long)TK[i] * TN[i];
        if (idx >= base && idx < base + sz) {
            long v = idx - base;
            int k = (int)(v / TN[i]);
            int n = (int)(v % TN[i]);
            p.out[i][(long)n * TK[i] + k] = p.in[i][v];
        }
        base += sz;
    }
}

// ---------------- pad attr [E,16] -> [E,32] (zeros in k>=16) ----------------
__global__ void pad_attr(const u16* __restrict__ a16, u16* __restrict__ a32) {
    long idx = (long)blockIdx.x * 256 + threadIdx.x;
    if (idx >= (long)EE * 32) return;
    int k = (int)(idx & 31);
    long e = idx >> 5;
    a32[idx] = (k < 16) ? a16[e * 16 + k] : (u16)0;
}
// w1 [16,256] -> padded BT layout [256][32] (zeros in k>=16)
__global__ void pad_w1t(const u16* __restrict__ w1, u16* __restrict__ w1t32) {
    int idx = blockIdx.x * 256 + threadIdx.x;
    if (idx >= 256 * 32) return;
    int k = idx & 31, n = idx >> 5;
    w1t32[idx] = (k < 16) ? w1[k * 256 + n] : (u16)0;
}

// ---- stage 128x32 bf16 tile via global_load_lds (128^2 path) ----
__device__ __forceinline__ void stage_tile(const u16* g, long row_base, long max_row,
                                           int kstride, int k0, u16* s, int t) {
    int wave = t >> 6;
    #pragma unroll
    for (int j = 0; j < 2; ++j) {
        int c = t + 256 * j;                 // chunk id 0..511 (16B each)
        long r = row_base + (c >> 2);        // 4 chunks per 32-elem row
        if (r > max_row) r = max_row;        // tail clamp (masked at C store)
        const u16* gp = g + r * (long)kstride + k0 + (c & 3) * 8;
        __builtin_amdgcn_global_load_lds(
            (__attribute__((address_space(1))) void*)(void*)gp,
            (__attribute__((address_space(3))) void*)((char*)s + wave * 1024 + j * 4096),
            16, 0, 0);                       // HW writes LDS at base + lane*16
    }
}

// C = ELU(A[M,K] @ BT[N,K]^T + bias), bf16 out. N mult of 128, K mult of 32.
// XCD-swizzled 1D grid. Used for edge-L1 (K=32), GIN g1 (K=64), GIN g2 (K=256).
__global__ __launch_bounds__(256)
void gemm_bt_bias_elu(const u16* __restrict__ A, const u16* __restrict__ BT,
                      const u16* __restrict__ bias, u16* __restrict__ C,
                      int M, int K, int N, int mpx, int lognt) {
    const int bid = blockIdx.x;
    const int xcd = bid & 7;
    const int j = bid >> 3;
    const int m_idx = xcd * mpx + (j >> lognt);
    const int n_idx = j & ((1 << lognt) - 1);
    const int num_m = (M + 127) >> 7;
    if (m_idx >= num_m) return;              // block-uniform; before any barrier

    __shared__ __align__(16) u16 sA[128 * 32];
    __shared__ __align__(16) u16 sB[128 * 32];
    const int t = threadIdx.x;
    const int lane = t & 63;
    const int wave = t >> 6;
    const int wr = wave >> 1, wc = wave & 1;
    const int quad = lane >> 4, l16 = lane & 15;
    const long m0 = (long)m_idx * 128;
    const int n0 = n_idx * 128;

    f32x4 acc[4][4];
    const f32x4 z4 = {0.f, 0.f, 0.f, 0.f};
    #pragma unroll
    for (int mi = 0; mi < 4; ++mi)
        #pragma unroll
        for (int ni = 0; ni < 4; ++ni)
            acc[mi][ni] = z4;

    for (int k0 = 0; k0 < K; k0 += 32) {
        stage_tile(A, m0, (long)M - 1, K, k0, sA, t);
        stage_tile(BT, n0, (long)N - 1, K, k0, sB, t);
        __syncthreads();
        frag8 af[4], bfv[4];
        #pragma unroll
        for (int mi = 0; mi < 4; ++mi)
            af[mi] = *(const frag8*)(sA + (wr * 64 + mi * 16 + l16) * 32 + quad * 8);
        #pragma unroll
        for (int ni = 0; ni < 4; ++ni)
            bfv[ni] = *(const frag8*)(sB + (wc * 64 + ni * 16 + l16) * 32 + quad * 8);
        #pragma unroll
        for (int mi = 0; mi < 4; ++mi)
            #pragma unroll
            for (int ni = 0; ni < 4; ++ni)
                acc[mi][ni] = __builtin_amdgcn_mfma_f32_16x16x32_bf16(af[mi], bfv[ni], acc[mi][ni], 0, 0, 0);
        __syncthreads();
    }

    #pragma unroll
    for (int mi = 0; mi < 4; ++mi) {
        #pragma unroll
        for (int r = 0; r < 4; ++r) {
            long row = m0 + wr * 64 + mi * 16 + quad * 4 + r;  // C/D: row = quad*4+reg
            if (row < M) {
                #pragma unroll
                for (int ni = 0; ni < 4; ++ni) {
                    int col = n0 + wc * 64 + ni * 16 + l16;    // C/D: col = lane&15
                    float v = acc[mi][ni][r] + bf2f(bias[col]);
                    C[row * (long)N + col] = f2bf(eluf(v));
                }
            }
        }
    }
}

// ---------------- 8-phase 256x256 GEMM core (R14 schedule, verified) ----------------
// LDS 128KB = buf{0,1} x {A0,A1,B0,B1} x 16KB; region = 128 rows x 64 k, row=128B,
// swizzle LDS[row][s] = global slot s^(row&7), separable -> folded base pointers.
// Phase: {reads; stage 1 region; [vmcnt(4) @ph4/8]; barrier; setprio; 16 MFMA;
// setprio; barrier}. Race ledger in R12-R14 comments (verified passing).

#define QPHASE(PA0, PA1, PB0, PB1, QM, QN, LDA, LDB, VMW, STREG, SG, SRB, SRM, SCL, SKT) \
  do {                                                                           \
    if (LDA) {                                                                   \
      _Pragma("unroll")                                                          \
      for (int mi = 0; mi < 4; ++mi) {                                           \
        av[mi][0] = *(const frag8*)((PA0) + ((QM) * 4 + mi) * 2048);             \
        av[mi][1] = *(const frag8*)((PA1) + ((QM) * 4 + mi) * 2048);             \
      }                                                                          \
    }                                                                            \
    if ((LDB) >= 0) {                                                            \
      _Pragma("unroll")                                                          \
      for (int ni = 0; ni < 2; ++ni) {                                           \
        bv[(LDB) & 1][ni][0] = *(const frag8*)((PB0) + (((LDB) & 1) * 2 + ni) * 2048); \
        bv[(LDB) & 1][ni][1] = *(const frag8*)((PB1) + (((LDB) & 1) * 2 + ni) * 2048); \
      }                                                                          \
    }                                                                            \
    stage((STREG), (SG), (SRB), (SRM), (SKT), (SCL));                            \
    if (VMW) asm volatile("s_waitcnt vmcnt(4)" ::: "memory");                    \
    __builtin_amdgcn_s_barrier();                                                \
    __builtin_amdgcn_s_setprio(1);                                               \
    _Pragma("unroll")                                                            \
    for (int kk = 0; kk < 2; ++kk) {                                             \
      _Pragma("unroll")                                                          \
      for (int mi = 0; mi < 4; ++mi) {                                           \
        _Pragma("unroll")                                                        \
        for (int ni = 0; ni < 2; ++ni) {                                         \
          acc[(QM) * 4 + mi][(QN) * 2 + ni] =                                    \
              __builtin_amdgcn_mfma_f32_16x16x32_bf16(                           \
                  av[mi][kk], bv[(QN)][ni][kk],                                  \
                  acc[(QM) * 4 + mi][(QN) * 2 + ni], 0, 0, 0);                   \
        }                                                                        \
      }                                                                          \
    }                                                                            \
    __builtin_amdgcn_s_setprio(0);                                               \
    __builtin_amdgcn_s_barrier();                                                \
  } while (0)

__global__ __launch_bounds__(512, 2)
void gemm256p(const u16* __restrict__ A, const u16* __restrict__ BT,
              const u16* __restrict__ bias, u16* __restrict__ C,
              int M, int K, int N, int mpx, int lognt) {
    const int bid = blockIdx.x;
    const int xcd = bid & 7;
    const int j = bid >> 3;
    const int m_idx = xcd * mpx + (j >> lognt);
    const int n_idx = j & ((1 << lognt) - 1);
    const int num_m = (M + 255) >> 8;
    if (m_idx >= num_m) return;              // block-uniform; before any barrier

    __shared__ __align__(16) u16 lds[2][4][8192];  // [buf][A0,A1,B0,B1][16KB]
    const int t = threadIdx.x;
    const int lane = t & 63;
    const int wave = t >> 6;          // 0..7
    const int wm = wave >> 2;         // 0..1 : M half (128 rows)
    const int wn = wave & 3;          // 0..3 : N quarter (64 cols)
    const int quad = lane >> 4, l16 = lane & 15;
    const long m0 = (long)m_idx * 256;
    const long n0 = (long)n_idx * 256;

    // folded LDS read bases (separable swizzle)
    const int aoff0 = l16 * 128 + ((quad ^ (l16 & 3)) << 4) + (((l16 >> 2) & 1) << 6);
    const int aoff1 = aoff0 ^ 64;                       // kk=1 flips byte-bit 6
    const int bex = (wn & 1) * 8192;
    const char* pAX0 = (const char*)&lds[0][wm][0] + aoff0;
    const char* pAX1 = (const char*)&lds[0][wm][0] + aoff1;
    const char* pAY0 = (const char*)&lds[1][wm][0] + aoff0;
    const char* pAY1 = (const char*)&lds[1][wm][0] + aoff1;
    const char* pBX0 = (const char*)&lds[0][2 + (wn >> 1)][0] + aoff0 + bex;
    const char* pBX1 = (const char*)&lds[0][2 + (wn >> 1)][0] + aoff1 + bex;
    const char* pBY0 = (const char*)&lds[1][2 + (wn >> 1)][0] + aoff0 + bex;
    const char* pBY1 = (const char*)&lds[1][2 + (wn >> 1)][0] + aoff1 + bex;

    // staging: chunk ck = wave*2+jj covers 8 rows (1KB); global 16B-slot
    // pre-swizzled g=(lane&7)^((lane>>3)&7) so swizzled read finds slot s^(row&7).
    const int gslot = (((lane & 7) ^ ((lane >> 3) & 7)) << 3);
    const int lane_row = lane >> 3;
    const long lane_go = (long)lane_row * K + gslot;

    auto stage = [&](u16* sreg, const u16* G, long rbase, long rmax, int kt, bool cl) {
        #pragma unroll
        for (int jj = 0; jj < 2; ++jj) {
            const int ck = wave * 2 + jj;
            const u16* gp;
            if (!cl) {
                gp = G + (rbase + ck * 8) * (long)K + ((long)kt << 6) + lane_go;
            } else {
                long r = rbase + ck * 8 + lane_row;
                if (r > rmax) r = rmax;      // tail clamp, masked at C store
                gp = G + r * (long)K + ((long)kt << 6) + gslot;
            }
            __builtin_amdgcn_global_load_lds(
                (__attribute__((address_space(1))) void*)(void*)gp,
                (__attribute__((address_space(3))) void*)((char*)sreg + ck * 1024),
                16, 0, 0);
        }
    };

    f32x4 acc[8][4];
    const f32x4 z4 = {0.f, 0.f, 0.f, 0.f};
    #pragma unroll
    for (int mi = 0; mi < 8; ++mi)
        #pragma unroll
        for (int ni = 0; ni < 4; ++ni)
            acc[mi][ni] = z4;
    frag8 av[4][2];
    frag8 bv[2][2][2];

    const int ntk = K >> 6;          // K multiple of 128 -> ntk even
    const int niter = ntk >> 1;
    const long MM = (long)M - 1, NMX = (long)N - 1;
    const bool aclamp = (m0 + 255) > MM;     // block-uniform

    stage(&lds[0][2][0], BT, n0,       NMX, 0, false);
    stage(&lds[0][3][0], BT, n0 + 128, NMX, 0, false);
    stage(&lds[0][0][0], A,  m0,       MM,  0, aclamp);
    stage(&lds[0][1][0], A,  m0 + 128, MM,  0, aclamp);
    stage(&lds[1][2][0], BT, n0,       NMX, 1, false);
    stage(&lds[1][3][0], BT, n0 + 128, NMX, 1, false);
    asm volatile("s_waitcnt vmcnt(4)" ::: "memory");   // tile0's 8 loads landed
    __builtin_amdgcn_s_barrier();

    for (int it = 0; it < niter; ++it) {
        const int t1k = 2 * it + 1;
        int t2k = 2 * it + 2; if (t2k > ntk - 1) t2k = ntk - 1;
        int t3k = 2 * it + 3; if (t3k > ntk - 1) t3k = ntk - 1;

        QPHASE(pAX0, pAX1, pBX0, pBX1, 0, 0, 1,  0, 0, &lds[1][0][0], A,  m0,       MM,  aclamp, t1k);
        QPHASE(pAX0, pAX1, pBX0, pBX1, 0, 1, 0,  1, 0, &lds[1][1][0], A,  m0 + 128, MM,  aclamp, t1k);
        QPHASE(pAX0, pAX1, pBX0, pBX1, 1, 0, 1, -1, 0, &lds[0][2][0], BT, n0,       NMX, false,  t2k);
        QPHASE(pAX0, pAX1, pBX0, pBX1, 1, 1, 0, -1, 1, &lds[0][3][0], BT, n0 + 128, NMX, false,  t2k);
        QPHASE(pAY0, pAY1, pBY0, pBY1, 0, 0, 1,  0, 0, &lds[0][0][0], A,  m0,       MM,  aclamp, t2k);
        QPHASE(pAY0, pAY1, pBY0, pBY1, 0, 1, 0,  1, 0, &lds[0][1][0], A,  m0 + 128, MM,  aclamp, t2k);
        QPHASE(pAY0, pAY1, pBY0, pBY1, 1, 0, 1, -1, 0, &lds[1][2][0], BT, n0,       NMX, false,  t3k);
        QPHASE(pAY0, pAY1, pBY0, pBY1, 1, 1, 0, -1, 1, &lds[1][3][0], BT, n0 + 128, NMX, false,  t3k);
    }
    asm volatile("s_waitcnt vmcnt(0)" ::: "memory");   // drain leftover stages

    #pragma unroll
    for (int mi = 0; mi < 8; ++mi) {
        #pragma unroll
        for (int r = 0; r < 4; ++r) {
            long row = m0 + wm * 128 + mi * 16 + quad * 4 + r;   // C/D: row = quad*4+reg
            if (row < M) {
                #pragma unroll
                for (int ni = 0; ni < 4; ++ni) {
                    long col = n0 + wn * 64 + ni * 16 + l16;     // C/D: col = lane&15
                    float v = acc[mi][ni][r] + bf2f(bias[col]);
                    C[row * (long)N + col] = f2bf(eluf(v));
                }
            }
        }
    }
}

// C[M,64] fp32 = A[M,K] @ BT[64,K]^T + bias (no ELU). M-tile 256, N=64, K mult of 32.
__global__ __launch_bounds__(256)
void gemm_bt_f32(const u16* __restrict__ A, const u16* __restrict__ BT,
                 const u16* __restrict__ bias, float* __restrict__ C,
                 int M, int K) {
    __shared__ __align__(16) u16 sA[256 * 32];
    __shared__ __align__(16) u16 sB[64 * 32];
    const int t = threadIdx.x;
    const int lane = t & 63;
    const int wave = t >> 6;
    const int quad = lane >> 4, l16 = lane & 15;
    const long m0 = (long)blockIdx.x * 256;

    f32x4 acc[4][4];
    const f32x4 z4 = {0.f, 0.f, 0.f, 0.f};
    #pragma unroll
    for (int mi = 0; mi < 4; ++mi)
        #pragma unroll
        for (int ni = 0; ni < 4; ++ni)
            acc[mi][ni] = z4;

    for (int k0 = 0; k0 < K; k0 += 32) {
        #pragma unroll
        for (int j = 0; j < 4; ++j) {
            int c = t + 256 * j;
            long r = m0 + (c >> 2);
            if (r > (long)M - 1) r = (long)M - 1;
            const u16* gp = A + r * (long)K + k0 + (c & 3) * 8;
            __builtin_amdgcn_global_load_lds(
                (__attribute__((address_space(1))) void*)(void*)gp,
                (__attribute__((address_space(3))) void*)((char*)sA + wave * 1024 + j * 4096),
                16, 0, 0);
        }
        {
            int c = t;
            const u16* gp = BT + (long)(c >> 2) * K + k0 + (c & 3) * 8;
            __builtin_amdgcn_global_load_lds(
                (__attribute__((address_space(1))) void*)(void*)gp,
                (__attribute__((address_space(3))) void*)((char*)sB + wave * 1024),
                16, 0, 0);
        }
        __syncthreads();
        frag8 af[4], bfv[4];
        #pragma unroll
        for (int mi = 0; mi < 4; ++mi)
            af[mi] = *(const frag8*)(sA + (wave * 64 + mi * 16 + l16) * 32 + quad * 8);
        #pragma unroll
        for (int ni = 0; ni < 4; ++ni)
            bfv[ni] = *(const frag8*)(sB + (ni * 16 + l16) * 32 + quad * 8);
        #pragma unroll
        for (int mi = 0; mi < 4; ++mi)
            #pragma unroll
            for (int ni = 0; ni < 4; ++ni)
                acc[mi][ni] = __builtin_amdgcn_mfma_f32_16x16x32_bf16(af[mi], bfv[ni], acc[mi][ni], 0, 0, 0);
        __syncthreads();
    }

    #pragma unroll
    for (int mi = 0; mi < 4; ++mi) {
        #pragma unroll
        for (int r = 0; r < 4; ++r) {
            long row = m0 + wave * 64 + mi * 16 + quad * 4 + r;
            if (row < M) {
                #pragma unroll
                for (int ni = 0; ni < 4; ++ni) {
                    int col = ni * 16 + l16;
                    C[row * 64 + col] = acc[mi][ni][r] + bf2f(bias[col]);
                }
            }
        }
    }
}

// msg[e,o] = sum_i x[src[e],i] * we[e, i*64+o]; atomicAdd into agg[dst[e],o]
__global__ void nnconv_msg(const u16* __restrict__ we, const u16* __restrict__ x,
                           const int* __restrict__ src, const int* __restrict__ dst,
                           float* __restrict__ agg, int ce) {
    long idx = (long)blockIdx.x * 256 + threadIdx.x;
    if (idx >= (long)ce * 64) return;
    int o = (int)(idx & 63);
    long e = idx >> 6;
    const u16* wr = we + e * 1024;
    const u16* xr = x + (long)src[e] * 16;
    float v = 0.f;
    #pragma unroll
    for (int i = 0; i < 16; ++i)
        v += bf2f(xr[i]) * bf2f(wr[i * 64 + o]);
    atomicAdd(&agg[(long)dst[e] * 64 + o], v);
}

// ---- x_cur(emb0) = x @ root_w + root_b + agg (in-place on agg) ----
__global__ void add_root(const u16* __restrict__ x, const u16* __restrict__ rw,
                         const u16* __restrict__ rb, float* __restrict__ xcur) {
    long idx = (long)blockIdx.x * 256 + threadIdx.x;
    if (idx >= (long)NN * 64) return;
    int d = (int)(idx & 63);
    long n = idx >> 6;
    float v = bf2f(rb[d]);
    #pragma unroll
    for (int i = 0; i < 16; ++i)
        v += bf2f(x[n * 16 + i]) * bf2f(rw[i * 64 + d]);
    xcur[idx] += v;
}

// elu to bf16 AND zero the nbr accumulator (same index space; kills a memset launch)
__global__ void elu_zero(const float* __restrict__ in, u16* __restrict__ o,
                         float* __restrict__ nbr, long n) {
    long idx = (long)blockIdx.x * 256 + threadIdx.x;
    if (idx < n) { o[idx] = f2bf(eluf(in[idx])); nbr[idx] = 0.f; }
}

__global__ void gin_scatter(const u16* __restrict__ xin, const int* __restrict__ src,
                            const int* __restrict__ dst, float* __restrict__ nbr) {
    long idx = (long)blockIdx.x * 256 + threadIdx.x;
    if (idx >= (long)EE * 64) return;
    int d = (int)(idx & 63);
    long e = idx >> 6;
    atomicAdd(&nbr[(long)dst[e] * 64 + d], bf2f(xin[(long)src[e] * 64 + d]));
}

__global__ void gin_combine(const u16* __restrict__ xin, const float* __restrict__ nbr,
                            u16* __restrict__ hin, long n) {
    long idx = (long)blockIdx.x * 256 + threadIdx.x;
    if (idx < n) hin[idx] = f2bf(bf2f(xin[idx]) + nbr[idx]);
}

// out[n,d,l] = emb_l[n*64+d] -- one float4 per (n,d), fully coalesced
__global__ void write_out(const float* __restrict__ e0, const float* __restrict__ e1,
                          const float* __restrict__ e2, const float* __restrict__ e3,
                          float* __restrict__ out) {
    long idx = (long)blockIdx.x * 256 + threadIdx.x;
    if (idx >= (long)NN * 64) return;
    float4 v = {e0[idx], e1[idx], e2[idx], e3[idx]};
    *(float4*)(out + idx * 4) = v;
}

extern "C" void kernel_launch(void* const* d_in, const int* in_sizes, int n_in,
                              void* d_out, int out_size, void* d_ws, size_t ws_size,
                              hipStream_t stream) {
    (void)in_sizes; (void)n_in; (void)out_size;
    const void* eidx = d_in[1];
    float* out = (float*)d_out;   // reference output dtype = float32

    char* ws = (char*)d_ws;
    size_t off = 0;
    auto alloc = [&](size_t bytes) {
        char* p = ws + off;
        off += (bytes + 255) & ~(size_t)255;
        return p;
    };
    // ---- persistent ----
    int* src32 = (int*)alloc((size_t)EE * 4);
    int* dst32 = (int*)alloc((size_t)EE * 4);
    int* flag  = (int*)alloc(256);
    int* cnt   = (int*)alloc(256);
    const int cv_idx[16] = {0, 2, 3, 4, 5, 6, 7, 8, 9, 10, 11, 12, 13, 14, 15, 16};
    const long cv_n[16]  = {800000, 3200000, 4096, 256, 262144, 1024, 1048576, 1024,
                            1024, 64, 49152, 768, 196608, 768, 49152, 192};
    u16* cv[16];
    for (int i = 0; i < 16; ++i) cv[i] = (u16*)alloc((size_t)cv_n[i] * 2);
    u16 *xc = cv[0], *eac = cv[1], *w1c = cv[2], *b1c = cv[3], *w2c = cv[4], *b2c = cv[5],
        *w3c = cv[6], *b3c = cv[7], *rwc = cv[8], *rbc = cv[9],
        *g1c = cv[10], *gb1c = cv[11], *g2c = cv[12], *gb2c = cv[13], *g3c = cv[14], *gb3c = cv[15];
    u16* w2t = (u16*)alloc((size_t)1024 * 256 * 2);
    u16* w3t = (u16*)alloc((size_t)1024 * 1024 * 2);
    u16* g1t = (u16*)alloc((size_t)3 * 256 * 64 * 2);
    u16* g2t = (u16*)alloc((size_t)3 * 256 * 256 * 2);
    u16* g3t = (u16*)alloc((size_t)3 * 64 * 256 * 2);
    u16* attr32 = (u16*)alloc((size_t)EE * 32 * 2);   // padded edge_attr, K=32
    u16* w1t32  = (u16*)alloc((size_t)256 * 32 * 2);  // padded w1^T [256][32]
    // per-layer node embeddings, fp32 [N,64]; emb[0] doubles as agg/x_cur
    float* emb[4];
    for (int l = 0; l < 4; ++l) emb[l] = (float*)alloc((size_t)NN * 64 * 4);
    float* agg = emb[0];
    char* scratch = (char*)alloc(0);
    size_t avail = (ws_size > off + 4096) ? (ws_size - off - 4096) : 0;

    // ---- NNConv edge-chunk: h1c (512 B/e) + h2c (2048 B/e) + wec (2048 B/e) ----
    long CE = (long)(avail / 4608) & ~255L;
    if (CE < 256) CE = 256;
    if (CE > 200192) CE = 200192;
    u16* h1c = (u16*)scratch;
    u16* h2c = (u16*)(scratch + (size_t)CE * 512);
    u16* wec = (u16*)(scratch + (size_t)CE * 2560);

    // ---- GIN node-chunk: nbr+xin fixed (19.2MB) + 1152 B/node ----
    long gin_fixed = (long)NN * 64 * 4 + (long)NN * 64 * 2;
    long gin_avail = (long)avail - gin_fixed;
    if (gin_avail < 0) gin_avail = 0;
    long CN = (gin_avail / 1152) & ~255L;
    if (CN < 256) CN = 256;
    if (CN > 50176) CN = 50176;
    float* nbr = (float*)scratch;
    u16* xin   = (u16*)(scratch + (size_t)NN * 64 * 4);
    u16* hin   = (u16*)(scratch + gin_fixed);
    u16* hg1   = hin + (size_t)CN * 64;
    u16* hg2   = hg1 + (size_t)CN * 256;

    auto cdiv = [](long a, long b) { return (unsigned)((a + b - 1) / b); };

    // dtype probe on x, then normalize all float inputs to bf16 (ONE batched launch)
    hipMemsetAsync(cnt, 0, 4, stream);
    probe_f32<<<1, 256, 0, stream>>>((const u16*)d_in[0], cnt);
    {
        CvtPtrs cp;
        for (int i = 0; i < 16; ++i) { cp.src[i] = d_in[cv_idx[i]]; cp.dst[i] = cv[i]; }
        long total = 0;
        for (int i = 0; i < 16; ++i) total += cv_n[i];
        cvt_all<<<cdiv(total, 256), 256, 0, stream>>>(cp, cnt);
    }

    // edge_index conversion (layout-robust)
    hipMemsetAsync(flag, 0, 4, stream);
    detect_idx64<<<cdiv(EE, 256), 256, 0, stream>>>((const unsigned long long*)eidx, flag);
    convert_idx<<<cdiv(EE, 256), 256, 0, stream>>>(eidx, flag, src32, dst32);

    // weight transposes [K,N] -> [N,K] (ONE batched launch; order matches TK/TN tables)
    {
        TransPtrs tp;
        tp.in[0] = w2c;  tp.out[0] = w2t;
        tp.in[1] = w3c;  tp.out[1] = w3t;
        for (int l = 0; l < 3; ++l) {
            tp.in[2 + 3 * l] = g1c + l * 64 * 256;   tp.out[2 + 3 * l] = g1t + l * 256 * 64;
            tp.in[3 + 3 * l] = g2c + l * 256 * 256;  tp.out[3 + 3 * l] = g2t + l * 256 * 256;
            tp.in[4 + 3 * l] = g3c + l * 256 * 64;   tp.out[4 + 3 * l] = g3t + l * 64 * 256;
        }
        long total = 262144 + 1048576 + 3 * (16384 + 65536 + 16384);
        transpose_all<<<cdiv(total, 256), 256, 0, stream>>>(tp);
    }
    // pad attr K=16 -> K=32 (once) and w1 -> padded BT [256][32]
    pad_attr<<<cdiv((long)EE * 32, 256), 256, 0, stream>>>(eac, attr32);
    pad_w1t<<<cdiv(256 * 32, 256), 256, 0, stream>>>(w1c, w1t32);

    // ---- NNConv (edge-chunked) ----
    hipMemsetAsync(agg, 0, (size_t)NN * 64 * 4, stream);
    for (long e0 = 0; e0 < EE; e0 += CE) {
        int ce = (int)((EE - e0 < CE) ? (EE - e0) : CE);
        int mpx  = cdiv(cdiv(ce, 128), 8);
        int mpx2 = cdiv(cdiv(ce, 256), 8);
        gemm_bt_bias_elu<<<8 * mpx * 2, 256, 0, stream>>>(attr32 + e0 * 32, w1t32, b1c, h1c, ce, 32, 256, mpx, 1);
        gemm256p<<<8 * mpx2 * 4, 512, 0, stream>>>(h1c, w2t, b2c, h2c, ce, 256, 1024, mpx2, 2);
        gemm256p<<<8 * mpx2 * 4, 512, 0, stream>>>(h2c, w3t, b3c, wec, ce, 1024, 1024, mpx2, 2);
        nnconv_msg<<<cdiv((long)ce * 64, 256), 256, 0, stream>>>(wec, xc, src32 + e0, dst32 + e0, agg, ce);
    }
    add_root<<<cdiv((long)NN * 64, 256), 256, 0, stream>>>(xc, rwc, rbc, agg);

    // ---- 3x GINConv (node-chunked MLP) ----
    for (int l = 0; l < 3; ++l) {
        elu_zero<<<cdiv((long)NN * 64, 256), 256, 0, stream>>>(emb[l], xin, nbr, (long)NN * 64);
        gin_scatter<<<cdiv((long)EE * 64, 256), 256, 0, stream>>>(xin, src32, dst32, nbr);
        for (long n0 = 0; n0 < NN; n0 += CN) {
            int cn = (int)((NN - n0 < CN) ? (NN - n0) : CN);
            int mpx = cdiv(cdiv(cn, 128), 8);
            gin_combine<<<cdiv((long)cn * 64, 256), 256, 0, stream>>>(xin + n0 * 64, nbr + n0 * 64, hin, (long)cn * 64);
            gemm_bt_bias_elu<<<8 * mpx * 2, 256, 0, stream>>>(hin, g1t + l * 256 * 64, gb1c + l * 256, hg1, cn, 64, 256, mpx, 1);
            gemm_bt_bias_elu<<<8 * mpx * 2, 256, 0, stream>>>(hg1, g2t + l * 256 * 256, gb2c + l * 256, hg2, cn, 256, 256, mpx, 1);
            gemm_bt_f32<<<cdiv(cn, 256), 256, 0, stream>>>(hg2, g3t + l * 64 * 256, gb3c + l * 64, emb[l + 1] + n0 * 64, cn, 256);
        }
    }
    write_out<<<cdiv((long)NN * 64, 256), 256, 0, stream>>>(emb[0], emb[1], emb[2], emb[3], out);
}

// Round 10
// 1467.477 us; speedup vs baseline: 1.0831x; 1.0424x over previous
//
#include <hip/hip_runtime.h>
#include <hip/hip_bf16.h>

// GraphEncoder: NNConv (edge-MLP 16->256->1024->1024 + einsum + scatter) + 3x GINConv.
// R16: 1529us. gemm256p 126us plateau (MfmaUtil 27.6, conflicts 0). Signal:
// OccupancyPercent 17% vs 25% max for 8-wave/1-block-CU -> 640-block grid runs
// 3 rounds {256,256,128}; last round half-idle = ~17% makespan waste. Grid
// quantization, applies to every enn-L2/L3 dispatch.
// R17 (container flake; CE logic re-audited, no fault found -> resubmit as R18):
// round-exact grids. CE=32768 -> grid = CE/64 = 512 = exactly 2 full rounds,
// num_m=128=8x16 (zero dead blocks). 7 chunks (+8 launches ~20us), ws 151MB
// (guarded). Everything else identical to R16.
// Prediction: enn-L3 per-chunk 101us (null) vs 84-88us (makespan theory); occ
// 17->23-25. Null => structure at ceiling, pivot to scatter/CSR.

#define NN 50000
#define EE 200000

typedef unsigned short u16;
typedef __attribute__((ext_vector_type(8))) short frag8;
typedef __attribute__((ext_vector_type(4))) float f32x4;

__device__ __forceinline__ float bf2f(u16 u) {
    union { unsigned int i; float f; } v; v.i = ((unsigned int)u) << 16; return v.f;
}
__device__ __forceinline__ u16 f2bf(float f) {
    union { float f; unsigned int i; } v; v.f = f;
    return (u16)((v.i + 0x7fffu + ((v.i >> 16) & 1u)) >> 16);
}
__device__ __forceinline__ float eluf(float v) {
    return v > 0.f ? v : __expf(v) - 1.f;
}

// ---------------- float dtype probe: fp32-as-bf16 shows crazy exponents ----------------
__global__ void probe_f32(const u16* __restrict__ raw, int* __restrict__ cnt) {
    int t = threadIdx.x;  // single block of 256
    int c = 0;
    for (int j = t; j < 1024; j += 256) {
        unsigned e = (raw[j] >> 7) & 0xFF;
        if (e >= 0xBF) c++;   // |v| >= 2^64: never in genuine N(0,1)-ish bf16 data
    }
    if (c) atomicAdd(cnt, c);
}

// ---------------- batched bf16 normalize: 16 tensors in one launch ----------------
struct CvtPtrs { const void* src[16]; u16* dst[16]; };
__global__ void cvt_all(CvtPtrs p, const int* __restrict__ cnt) {
    constexpr long L[16] = {800000, 3200000, 4096, 256, 262144, 1024, 1048576, 1024,
                            1024, 64, 49152, 768, 196608, 768, 49152, 192};
    long idx = (long)blockIdx.x * 256 + threadIdx.x;
    const bool isf32 = (*cnt >= 8);
    long base = 0;
    #pragma unroll
    for (int i = 0; i < 16; ++i) {
        if (idx >= base && idx < base + L[i]) {
            long k = idx - base;
            p.dst[i][k] = isf32 ? f2bf(((const float*)p.src[i])[k])
                                : ((const u16*)p.src[i])[k];
        }
        base += L[i];
    }
}

// ---------------- edge_index layout probe + conversion ----------------
__global__ void detect_idx64(const unsigned long long* __restrict__ p, int* __restrict__ flag) {
    long t = (long)blockIdx.x * 256 + threadIdx.x;
    if (t < EE) {
        unsigned long long v = p[t];
        if (v >> 31) atomicOr(flag, 1);   // int32-packed pairs have high bits set
    }
}
__global__ void convert_idx(const void* __restrict__ raw, const int* __restrict__ flag,
                            int* __restrict__ s_out, int* __restrict__ d_out) {
    long t = (long)blockIdx.x * 256 + threadIdx.x;
    if (t >= EE) return;
    if (*flag) {  // int32 layout
        const int* q = (const int*)raw;
        s_out[t] = q[t];
        d_out[t] = q[EE + t];
    } else {      // int64 layout
        const long long* q = (const long long*)raw;
        s_out[t] = (int)q[t];
        d_out[t] = (int)q[EE + t];
    }
}

// ---------------- batched bf16 transpose: 11 jobs [K,N]->[N,K] in one launch ----------
struct TransPtrs { const u16* in[11]; u16* out[11]; };
__global__ void transpose_all(TransPtrs p) {
    constexpr int TK[11] = {256, 1024, 64, 256, 256, 64, 256, 256, 64, 256, 256};
    constexpr int TN[11] = {1024, 1024, 256, 256, 64, 256, 256, 64, 256, 256, 64};
    long idx = (long)blockIdx.x * 256 + threadIdx.x;
    long base = 0;
    #pragma unroll
    for (int i = 0; i < 11; ++i) {
        const long sz = (long)TK[i] * TN[i];
        if (idx >= base && idx < base + sz) {
            long v = idx - base;
            int k = (int)(v / TN[i]);
            int n = (int)(v % TN[i]);
            p.out[i][(long)n * TK[i] + k] = p.in[i][v];
        }
        base += sz;
    }
}

// ---------------- pad attr [E,16] -> [E,32] (zeros in k>=16) ----------------
__global__ void pad_attr(const u16* __restrict__ a16, u16* __restrict__ a32) {
    long idx = (long)blockIdx.x * 256 + threadIdx.x;
    if (idx >= (long)EE * 32) return;
    int k = (int)(idx & 31);
    long e = idx >> 5;
    a32[idx] = (k < 16) ? a16[e * 16 + k] : (u16)0;
}
// w1 [16,256] -> padded BT layout [256][32] (zeros in k>=16)
__global__ void pad_w1t(const u16* __restrict__ w1, u16* __restrict__ w1t32) {
    int idx = blockIdx.x * 256 + threadIdx.x;
    if (idx >= 256 * 32) return;
    int k = idx & 31, n = idx >> 5;
    w1t32[idx] = (k < 16) ? w1[k * 256 + n] : (u16)0;
}

// ---- stage 128x32 bf16 tile via global_load_lds (128^2 path) ----
__device__ __forceinline__ void stage_tile(const u16* g, long row_base, long max_row,
                                           int kstride, int k0, u16* s, int t) {
    int wave = t >> 6;
    #pragma unroll
    for (int j = 0; j < 2; ++j) {
        int c = t + 256 * j;                 // chunk id 0..511 (16B each)
        long r = row_base + (c >> 2);        // 4 chunks per 32-elem row
        if (r > max_row) r = max_row;        // tail clamp (masked at C store)
        const u16* gp = g + r * (long)kstride + k0 + (c & 3) * 8;
        __builtin_amdgcn_global_load_lds(
            (__attribute__((address_space(1))) void*)(void*)gp,
            (__attribute__((address_space(3))) void*)((char*)s + wave * 1024 + j * 4096),
            16, 0, 0);                       // HW writes LDS at base + lane*16
    }
}

// C = ELU(A[M,K] @ BT[N,K]^T + bias), bf16 out. N mult of 128, K mult of 32.
// XCD-swizzled 1D grid. Used for edge-L1 (K=32), GIN g1 (K=64), GIN g2 (K=256).
__global__ __launch_bounds__(256)
void gemm_bt_bias_elu(const u16* __restrict__ A, const u16* __restrict__ BT,
                      const u16* __restrict__ bias, u16* __restrict__ C,
                      int M, int K, int N, int mpx, int lognt) {
    const int bid = blockIdx.x;
    const int xcd = bid & 7;
    const int j = bid >> 3;
    const int m_idx = xcd * mpx + (j >> lognt);
    const int n_idx = j & ((1 << lognt) - 1);
    const int num_m = (M + 127) >> 7;
    if (m_idx >= num_m) return;              // block-uniform; before any barrier

    __shared__ __align__(16) u16 sA[128 * 32];
    __shared__ __align__(16) u16 sB[128 * 32];
    const int t = threadIdx.x;
    const int lane = t & 63;
    const int wave = t >> 6;
    const int wr = wave >> 1, wc = wave & 1;
    const int quad = lane >> 4, l16 = lane & 15;
    const long m0 = (long)m_idx * 128;
    const int n0 = n_idx * 128;

    f32x4 acc[4][4];
    const f32x4 z4 = {0.f, 0.f, 0.f, 0.f};
    #pragma unroll
    for (int mi = 0; mi < 4; ++mi)
        #pragma unroll
        for (int ni = 0; ni < 4; ++ni)
            acc[mi][ni] = z4;

    for (int k0 = 0; k0 < K; k0 += 32) {
        stage_tile(A, m0, (long)M - 1, K, k0, sA, t);
        stage_tile(BT, n0, (long)N - 1, K, k0, sB, t);
        __syncthreads();
        frag8 af[4], bfv[4];
        #pragma unroll
        for (int mi = 0; mi < 4; ++mi)
            af[mi] = *(const frag8*)(sA + (wr * 64 + mi * 16 + l16) * 32 + quad * 8);
        #pragma unroll
        for (int ni = 0; ni < 4; ++ni)
            bfv[ni] = *(const frag8*)(sB + (wc * 64 + ni * 16 + l16) * 32 + quad * 8);
        #pragma unroll
        for (int mi = 0; mi < 4; ++mi)
            #pragma unroll
            for (int ni = 0; ni < 4; ++ni)
                acc[mi][ni] = __builtin_amdgcn_mfma_f32_16x16x32_bf16(af[mi], bfv[ni], acc[mi][ni], 0, 0, 0);
        __syncthreads();
    }

    #pragma unroll
    for (int mi = 0; mi < 4; ++mi) {
        #pragma unroll
        for (int r = 0; r < 4; ++r) {
            long row = m0 + wr * 64 + mi * 16 + quad * 4 + r;  // C/D: row = quad*4+reg
            if (row < M) {
                #pragma unroll
                for (int ni = 0; ni < 4; ++ni) {
                    int col = n0 + wc * 64 + ni * 16 + l16;    // C/D: col = lane&15
                    float v = acc[mi][ni][r] + bf2f(bias[col]);
                    C[row * (long)N + col] = f2bf(eluf(v));
                }
            }
        }
    }
}

// ---------------- 8-phase 256x256 GEMM core (R14 schedule, verified) ----------------
// LDS 128KB = buf{0,1} x {A0,A1,B0,B1} x 16KB; region = 128 rows x 64 k, row=128B,
// swizzle LDS[row][s] = global slot s^(row&7), separable -> folded base pointers.
// Phase: {reads; stage 1 region; [vmcnt(4) @ph4/8]; barrier; setprio; 16 MFMA;
// setprio; barrier}. Race ledger in R12-R14 comments (verified passing).

#define QPHASE(PA0, PA1, PB0, PB1, QM, QN, LDA, LDB, VMW, STREG, SG, SRB, SRM, SCL, SKT) \
  do {                                                                           \
    if (LDA) {                                                                   \
      _Pragma("unroll")                                                          \
      for (int mi = 0; mi < 4; ++mi) {                                           \
        av[mi][0] = *(const frag8*)((PA0) + ((QM) * 4 + mi) * 2048);             \
        av[mi][1] = *(const frag8*)((PA1) + ((QM) * 4 + mi) * 2048);             \
      }                                                                          \
    }                                                                            \
    if ((LDB) >= 0) {                                                            \
      _Pragma("unroll")                                                          \
      for (int ni = 0; ni < 2; ++ni) {                                           \
        bv[(LDB) & 1][ni][0] = *(const frag8*)((PB0) + (((LDB) & 1) * 2 + ni) * 2048); \
        bv[(LDB) & 1][ni][1] = *(const frag8*)((PB1) + (((LDB) & 1) * 2 + ni) * 2048); \
      }                                                                          \
    }                                                                            \
    stage((STREG), (SG), (SRB), (SRM), (SKT), (SCL));                            \
    if (VMW) asm volatile("s_waitcnt vmcnt(4)" ::: "memory");                    \
    __builtin_amdgcn_s_barrier();                                                \
    __builtin_amdgcn_s_setprio(1);                                               \
    _Pragma("unroll")                                                            \
    for (int kk = 0; kk < 2; ++kk) {                                             \
      _Pragma("unroll")                                                          \
      for (int mi = 0; mi < 4; ++mi) {                                           \
        _Pragma("unroll")                                                        \
        for (int ni = 0; ni < 2; ++ni) {                                         \
          acc[(QM) * 4 + mi][(QN) * 2 + ni] =                                    \
              __builtin_amdgcn_mfma_f32_16x16x32_bf16(                           \
                  av[mi][kk], bv[(QN)][ni][kk],                                  \
                  acc[(QM) * 4 + mi][(QN) * 2 + ni], 0, 0, 0);                   \
        }                                                                        \
      }                                                                          \
    }                                                                            \
    __builtin_amdgcn_s_setprio(0);                                               \
    __builtin_amdgcn_s_barrier();                                                \
  } while (0)

__global__ __launch_bounds__(512, 2)
void gemm256p(const u16* __restrict__ A, const u16* __restrict__ BT,
              const u16* __restrict__ bias, u16* __restrict__ C,
              int M, int K, int N, int mpx, int lognt) {
    const int bid = blockIdx.x;
    const int xcd = bid & 7;
    const int j = bid >> 3;
    const int m_idx = xcd * mpx + (j >> lognt);
    const int n_idx = j & ((1 << lognt) - 1);
    const int num_m = (M + 255) >> 8;
    if (m_idx >= num_m) return;              // block-uniform; before any barrier

    __shared__ __align__(16) u16 lds[2][4][8192];  // [buf][A0,A1,B0,B1][16KB]
    const int t = threadIdx.x;
    const int lane = t & 63;
    const int wave = t >> 6;          // 0..7
    const int wm = wave >> 2;         // 0..1 : M half (128 rows)
    const int wn = wave & 3;          // 0..3 : N quarter (64 cols)
    const int quad = lane >> 4, l16 = lane & 15;
    const long m0 = (long)m_idx * 256;
    const long n0 = (long)n_idx * 256;

    // folded LDS read bases (separable swizzle)
    const int aoff0 = l16 * 128 + ((quad ^ (l16 & 3)) << 4) + (((l16 >> 2) & 1) << 6);
    const int aoff1 = aoff0 ^ 64;                       // kk=1 flips byte-bit 6
    const int bex = (wn & 1) * 8192;
    const char* pAX0 = (const char*)&lds[0][wm][0] + aoff0;
    const char* pAX1 = (const char*)&lds[0][wm][0] + aoff1;
    const char* pAY0 = (const char*)&lds[1][wm][0] + aoff0;
    const char* pAY1 = (const char*)&lds[1][wm][0] + aoff1;
    const char* pBX0 = (const char*)&lds[0][2 + (wn >> 1)][0] + aoff0 + bex;
    const char* pBX1 = (const char*)&lds[0][2 + (wn >> 1)][0] + aoff1 + bex;
    const char* pBY0 = (const char*)&lds[1][2 + (wn >> 1)][0] + aoff0 + bex;
    const char* pBY1 = (const char*)&lds[1][2 + (wn >> 1)][0] + aoff1 + bex;

    // staging: chunk ck = wave*2+jj covers 8 rows (1KB); global 16B-slot
    // pre-swizzled g=(lane&7)^((lane>>3)&7) so swizzled read finds slot s^(row&7).
    const int gslot = (((lane & 7) ^ ((lane >> 3) & 7)) << 3);
    const int lane_row = lane >> 3;
    const long lane_go = (long)lane_row * K + gslot;

    auto stage = [&](u16* sreg, const u16* G, long rbase, long rmax, int kt, bool cl) {
        #pragma unroll
        for (int jj = 0; jj < 2; ++jj) {
            const int ck = wave * 2 + jj;
            const u16* gp;
            if (!cl) {
                gp = G + (rbase + ck * 8) * (long)K + ((long)kt << 6) + lane_go;
            } else {
                long r = rbase + ck * 8 + lane_row;
                if (r > rmax) r = rmax;      // tail clamp, masked at C store
                gp = G + r * (long)K + ((long)kt << 6) + gslot;
            }
            __builtin_amdgcn_global_load_lds(
                (__attribute__((address_space(1))) void*)(void*)gp,
                (__attribute__((address_space(3))) void*)((char*)sreg + ck * 1024),
                16, 0, 0);
        }
    };

    f32x4 acc[8][4];
    const f32x4 z4 = {0.f, 0.f, 0.f, 0.f};
    #pragma unroll
    for (int mi = 0; mi < 8; ++mi)
        #pragma unroll
        for (int ni = 0; ni < 4; ++ni)
            acc[mi][ni] = z4;
    frag8 av[4][2];
    frag8 bv[2][2][2];

    const int ntk = K >> 6;          // K multiple of 128 -> ntk even
    const int niter = ntk >> 1;
    const long MM = (long)M - 1, NMX = (long)N - 1;
    const bool aclamp = (m0 + 255) > MM;     // block-uniform

    stage(&lds[0][2][0], BT, n0,       NMX, 0, false);
    stage(&lds[0][3][0], BT, n0 + 128, NMX, 0, false);
    stage(&lds[0][0][0], A,  m0,       MM,  0, aclamp);
    stage(&lds[0][1][0], A,  m0 + 128, MM,  0, aclamp);
    stage(&lds[1][2][0], BT, n0,       NMX, 1, false);
    stage(&lds[1][3][0], BT, n0 + 128, NMX, 1, false);
    asm volatile("s_waitcnt vmcnt(4)" ::: "memory");   // tile0's 8 loads landed
    __builtin_amdgcn_s_barrier();

    for (int it = 0; it < niter; ++it) {
        const int t1k = 2 * it + 1;
        int t2k = 2 * it + 2; if (t2k > ntk - 1) t2k = ntk - 1;
        int t3k = 2 * it + 3; if (t3k > ntk - 1) t3k = ntk - 1;

        QPHASE(pAX0, pAX1, pBX0, pBX1, 0, 0, 1,  0, 0, &lds[1][0][0], A,  m0,       MM,  aclamp, t1k);
        QPHASE(pAX0, pAX1, pBX0, pBX1, 0, 1, 0,  1, 0, &lds[1][1][0], A,  m0 + 128, MM,  aclamp, t1k);
        QPHASE(pAX0, pAX1, pBX0, pBX1, 1, 0, 1, -1, 0, &lds[0][2][0], BT, n0,       NMX, false,  t2k);
        QPHASE(pAX0, pAX1, pBX0, pBX1, 1, 1, 0, -1, 1, &lds[0][3][0], BT, n0 + 128, NMX, false,  t2k);
        QPHASE(pAY0, pAY1, pBY0, pBY1, 0, 0, 1,  0, 0, &lds[0][0][0], A,  m0,       MM,  aclamp, t2k);
        QPHASE(pAY0, pAY1, pBY0, pBY1, 0, 1, 0,  1, 0, &lds[0][1][0], A,  m0 + 128, MM,  aclamp, t2k);
        QPHASE(pAY0, pAY1, pBY0, pBY1, 1, 0, 1, -1, 0, &lds[1][2][0], BT, n0,       NMX, false,  t3k);
        QPHASE(pAY0, pAY1, pBY0, pBY1, 1, 1, 0, -1, 1, &lds[1][3][0], BT, n0 + 128, NMX, false,  t3k);
    }
    asm volatile("s_waitcnt vmcnt(0)" ::: "memory");   // drain leftover stages

    #pragma unroll
    for (int mi = 0; mi < 8; ++mi) {
        #pragma unroll
        for (int r = 0; r < 4; ++r) {
            long row = m0 + wm * 128 + mi * 16 + quad * 4 + r;   // C/D: row = quad*4+reg
            if (row < M) {
                #pragma unroll
                for (int ni = 0; ni < 4; ++ni) {
                    long col = n0 + wn * 64 + ni * 16 + l16;     // C/D: col = lane&15
                    float v = acc[mi][ni][r] + bf2f(bias[col]);
                    C[row * (long)N + col] = f2bf(eluf(v));
                }
            }
        }
    }
}

// C[M,64] fp32 = A[M,K] @ BT[64,K]^T + bias (no ELU). M-tile 256, N=64, K mult of 32.
__global__ __launch_bounds__(256)
void gemm_bt_f32(const u16* __restrict__ A, const u16* __restrict__ BT,
                 const u16* __restrict__ bias, float* __restrict__ C,
                 int M, int K) {
    __shared__ __align__(16) u16 sA[256 * 32];
    __shared__ __align__(16) u16 sB[64 * 32];
    const int t = threadIdx.x;
    const int lane = t & 63;
    const int wave = t >> 6;
    const int quad = lane >> 4, l16 = lane & 15;
    const long m0 = (long)blockIdx.x * 256;

    f32x4 acc[4][4];
    const f32x4 z4 = {0.f, 0.f, 0.f, 0.f};
    #pragma unroll
    for (int mi = 0; mi < 4; ++mi)
        #pragma unroll
        for (int ni = 0; ni < 4; ++ni)
            acc[mi][ni] = z4;

    for (int k0 = 0; k0 < K; k0 += 32) {
        #pragma unroll
        for (int j = 0; j < 4; ++j) {
            int c = t + 256 * j;
            long r = m0 + (c >> 2);
            if (r > (long)M - 1) r = (long)M - 1;
            const u16* gp = A + r * (long)K + k0 + (c & 3) * 8;
            __builtin_amdgcn_global_load_lds(
                (__attribute__((address_space(1))) void*)(void*)gp,
                (__attribute__((address_space(3))) void*)((char*)sA + wave * 1024 + j * 4096),
                16, 0, 0);
        }
        {
            int c = t;
            const u16* gp = BT + (long)(c >> 2) * K + k0 + (c & 3) * 8;
            __builtin_amdgcn_global_load_lds(
                (__attribute__((address_space(1))) void*)(void*)gp,
                (__attribute__((address_space(3))) void*)((char*)sB + wave * 1024),
                16, 0, 0);
        }
        __syncthreads();
        frag8 af[4], bfv[4];
        #pragma unroll
        for (int mi = 0; mi < 4; ++mi)
            af[mi] = *(const frag8*)(sA + (wave * 64 + mi * 16 + l16) * 32 + quad * 8);
        #pragma unroll
        for (int ni = 0; ni < 4; ++ni)
            bfv[ni] = *(const frag8*)(sB + (ni * 16 + l16) * 32 + quad * 8);
        #pragma unroll
        for (int mi = 0; mi < 4; ++mi)
            #pragma unroll
            for (int ni = 0; ni < 4; ++ni)
                acc[mi][ni] = __builtin_amdgcn_mfma_f32_16x16x32_bf16(af[mi], bfv[ni], acc[mi][ni], 0, 0, 0);
        __syncthreads();
    }

    #pragma unroll
    for (int mi = 0; mi < 4; ++mi) {
        #pragma unroll
        for (int r = 0; r < 4; ++r) {
            long row = m0 + wave * 64 + mi * 16 + quad * 4 + r;
            if (row < M) {
                #pragma unroll
                for (int ni = 0; ni < 4; ++ni) {
                    int col = ni * 16 + l16;
                    C[row * 64 + col] = acc[mi][ni][r] + bf2f(bias[col]);
                }
            }
        }
    }
}

// msg[e,o] = sum_i x[src[e],i] * we[e, i*64+o]; atomicAdd into agg[dst[e],o]
__global__ void nnconv_msg(const u16* __restrict__ we, const u16* __restrict__ x,
                           const int* __restrict__ src, const int* __restrict__ dst,
                           float* __restrict__ agg, int ce) {
    long idx = (long)blockIdx.x * 256 + threadIdx.x;
    if (idx >= (long)ce * 64) return;
    int o = (int)(idx & 63);
    long e = idx >> 6;
    const u16* wr = we + e * 1024;
    const u16* xr = x + (long)src[e] * 16;
    float v = 0.f;
    #pragma unroll
    for (int i = 0; i < 16; ++i)
        v += bf2f(xr[i]) * bf2f(wr[i * 64 + o]);
    atomicAdd(&agg[(long)dst[e] * 64 + o], v);
}

// ---- x_cur(emb0) = x @ root_w + root_b + agg (in-place on agg) ----
__global__ void add_root(const u16* __restrict__ x, const u16* __restrict__ rw,
                         const u16* __restrict__ rb, float* __restrict__ xcur) {
    long idx = (long)blockIdx.x * 256 + threadIdx.x;
    if (idx >= (long)NN * 64) return;
    int d = (int)(idx & 63);
    long n = idx >> 6;
    float v = bf2f(rb[d]);
    #pragma unroll
    for (int i = 0; i < 16; ++i)
        v += bf2f(x[n * 16 + i]) * bf2f(rw[i * 64 + d]);
    xcur[idx] += v;
}

// elu to bf16 AND zero the nbr accumulator (same index space; kills a memset launch)
__global__ void elu_zero(const float* __restrict__ in, u16* __restrict__ o,
                         float* __restrict__ nbr, long n) {
    long idx = (long)blockIdx.x * 256 + threadIdx.x;
    if (idx < n) { o[idx] = f2bf(eluf(in[idx])); nbr[idx] = 0.f; }
}

__global__ void gin_scatter(const u16* __restrict__ xin, const int* __restrict__ src,
                            const int* __restrict__ dst, float* __restrict__ nbr) {
    long idx = (long)blockIdx.x * 256 + threadIdx.x;
    if (idx >= (long)EE * 64) return;
    int d = (int)(idx & 63);
    long e = idx >> 6;
    atomicAdd(&nbr[(long)dst[e] * 64 + d], bf2f(xin[(long)src[e] * 64 + d]));
}

__global__ void gin_combine(const u16* __restrict__ xin, const float* __restrict__ nbr,
                            u16* __restrict__ hin, long n) {
    long idx = (long)blockIdx.x * 256 + threadIdx.x;
    if (idx < n) hin[idx] = f2bf(bf2f(xin[idx]) + nbr[idx]);
}

// out[n,d,l] = emb_l[n*64+d] -- one float4 per (n,d), fully coalesced
__global__ void write_out(const float* __restrict__ e0, const float* __restrict__ e1,
                          const float* __restrict__ e2, const float* __restrict__ e3,
                          float* __restrict__ out) {
    long idx = (long)blockIdx.x * 256 + threadIdx.x;
    if (idx >= (long)NN * 64) return;
    float4 v = {e0[idx], e1[idx], e2[idx], e3[idx]};
    *(float4*)(out + idx * 4) = v;
}

extern "C" void kernel_launch(void* const* d_in, const int* in_sizes, int n_in,
                              void* d_out, int out_size, void* d_ws, size_t ws_size,
                              hipStream_t stream) {
    (void)in_sizes; (void)n_in; (void)out_size;
    const void* eidx = d_in[1];
    float* out = (float*)d_out;   // reference output dtype = float32

    char* ws = (char*)d_ws;
    size_t off = 0;
    auto alloc = [&](size_t bytes) {
        char* p = ws + off;
        off += (bytes + 255) & ~(size_t)255;
        return p;
    };
    // ---- persistent ----
    int* src32 = (int*)alloc((size_t)EE * 4);
    int* dst32 = (int*)alloc((size_t)EE * 4);
    int* flag  = (int*)alloc(256);
    int* cnt   = (int*)alloc(256);
    const int cv_idx[16] = {0, 2, 3, 4, 5, 6, 7, 8, 9, 10, 11, 12, 13, 14, 15, 16};
    const long cv_n[16]  = {800000, 3200000, 4096, 256, 262144, 1024, 1048576, 1024,
                            1024, 64, 49152, 768, 196608, 768, 49152, 192};
    u16* cv[16];
    for (int i = 0; i < 16; ++i) cv[i] = (u16*)alloc((size_t)cv_n[i] * 2);
    u16 *xc = cv[0], *eac = cv[1], *w1c = cv[2], *b1c = cv[3], *w2c = cv[4], *b2c = cv[5],
        *w3c = cv[6], *b3c = cv[7], *rwc = cv[8], *rbc = cv[9],
        *g1c = cv[10], *gb1c = cv[11], *g2c = cv[12], *gb2c = cv[13], *g3c = cv[14], *gb3c = cv[15];
    u16* w2t = (u16*)alloc((size_t)1024 * 256 * 2);
    u16* w3t = (u16*)alloc((size_t)1024 * 1024 * 2);
    u16* g1t = (u16*)alloc((size_t)3 * 256 * 64 * 2);
    u16* g2t = (u16*)alloc((size_t)3 * 256 * 256 * 2);
    u16* g3t = (u16*)alloc((size_t)3 * 64 * 256 * 2);
    u16* attr32 = (u16*)alloc((size_t)EE * 32 * 2);   // padded edge_attr, K=32
    u16* w1t32  = (u16*)alloc((size_t)256 * 32 * 2);  // padded w1^T [256][32]
    // per-layer node embeddings, fp32 [N,64]; emb[0] doubles as agg/x_cur
    float* emb[4];
    for (int l = 0; l < 4; ++l) emb[l] = (float*)alloc((size_t)NN * 64 * 4);
    float* agg = emb[0];
    char* scratch = (char*)alloc(0);
    size_t avail = (ws_size > off + 4096) ? (ws_size - off - 4096) : 0;

    // ---- NNConv edge-chunk: h1c (512 B/e) + h2c (2048 B/e) + wec (2048 B/e) ----
    // Round-exact grids: CE multiple of 16384 -> grid = CE/64 multiple of 256
    // (full CU rounds, zero idle blocks). Prefer 32768 (2 rounds/dispatch).
    long CE = (long)(avail / 4608);
    if (CE >= 32768) CE = 32768;
    else {
        long q = CE & ~16383L;               // largest multiple of 16384 that fits
        CE = (q >= 16384) ? q : (CE & ~255L);
    }
    if (CE < 256) CE = 256;
    u16* h1c = (u16*)scratch;
    u16* h2c = (u16*)(scratch + (size_t)CE * 512);
    u16* wec = (u16*)(scratch + (size_t)CE * 2560);

    // ---- GIN node-chunk: nbr+xin fixed (19.2MB) + 1152 B/node ----
    long gin_fixed = (long)NN * 64 * 4 + (long)NN * 64 * 2;
    long gin_avail = (long)avail - gin_fixed;
    if (gin_avail < 0) gin_avail = 0;
    long CN = (gin_avail / 1152) & ~255L;
    if (CN < 256) CN = 256;
    if (CN > 50176) CN = 50176;
    float* nbr = (float*)scratch;
    u16* xin   = (u16*)(scratch + (size_t)NN * 64 * 4);
    u16* hin   = (u16*)(scratch + gin_fixed);
    u16* hg1   = hin + (size_t)CN * 64;
    u16* hg2   = hg1 + (size_t)CN * 256;

    auto cdiv = [](long a, long b) { return (unsigned)((a + b - 1) / b); };

    // dtype probe on x, then normalize all float inputs to bf16 (ONE batched launch)
    hipMemsetAsync(cnt, 0, 4, stream);
    probe_f32<<<1, 256, 0, stream>>>((const u16*)d_in[0], cnt);
    {
        CvtPtrs cp;
        for (int i = 0; i < 16; ++i) { cp.src[i] = d_in[cv_idx[i]]; cp.dst[i] = cv[i]; }
        long total = 0;
        for (int i = 0; i < 16; ++i) total += cv_n[i];
        cvt_all<<<cdiv(total, 256), 256, 0, stream>>>(cp, cnt);
    }

    // edge_index conversion (layout-robust)
    hipMemsetAsync(flag, 0, 4, stream);
    detect_idx64<<<cdiv(EE, 256), 256, 0, stream>>>((const unsigned long long*)eidx, flag);
    convert_idx<<<cdiv(EE, 256), 256, 0, stream>>>(eidx, flag, src32, dst32);

    // weight transposes [K,N] -> [N,K] (ONE batched launch; order matches TK/TN tables)
    {
        TransPtrs tp;
        tp.in[0] = w2c;  tp.out[0] = w2t;
        tp.in[1] = w3c;  tp.out[1] = w3t;
        for (int l = 0; l < 3; ++l) {
            tp.in[2 + 3 * l] = g1c + l * 64 * 256;   tp.out[2 + 3 * l] = g1t + l * 256 * 64;
            tp.in[3 + 3 * l] = g2c + l * 256 * 256;  tp.out[3 + 3 * l] = g2t + l * 256 * 256;
            tp.in[4 + 3 * l] = g3c + l * 256 * 64;   tp.out[4 + 3 * l] = g3t + l * 64 * 256;
        }
        long total = 262144 + 1048576 + 3 * (16384 + 65536 + 16384);
        transpose_all<<<cdiv(total, 256), 256, 0, stream>>>(tp);
    }
    // pad attr K=16 -> K=32 (once) and w1 -> padded BT [256][32]
    pad_attr<<<cdiv((long)EE * 32, 256), 256, 0, stream>>>(eac, attr32);
    pad_w1t<<<cdiv(256 * 32, 256), 256, 0, stream>>>(w1c, w1t32);

    // ---- NNConv (edge-chunked) ----
    hipMemsetAsync(agg, 0, (size_t)NN * 64 * 4, stream);
    for (long e0 = 0; e0 < EE; e0 += CE) {
        int ce = (int)((EE - e0 < CE) ? (EE - e0) : CE);
        int mpx  = cdiv(cdiv(ce, 128), 8);
        int mpx2 = cdiv(cdiv(ce, 256), 8);
        gemm_bt_bias_elu<<<8 * mpx * 2, 256, 0, stream>>>(attr32 + e0 * 32, w1t32, b1c, h1c, ce, 32, 256, mpx, 1);
        gemm256p<<<8 * mpx2 * 4, 512, 0, stream>>>(h1c, w2t, b2c, h2c, ce, 256, 1024, mpx2, 2);
        gemm256p<<<8 * mpx2 * 4, 512, 0, stream>>>(h2c, w3t, b3c, wec, ce, 1024, 1024, mpx2, 2);
        nnconv_msg<<<cdiv((long)ce * 64, 256), 256, 0, stream>>>(wec, xc, src32 + e0, dst32 + e0, agg, ce);
    }
    add_root<<<cdiv((long)NN * 64, 256), 256, 0, stream>>>(xc, rwc, rbc, agg);

    // ---- 3x GINConv (node-chunked MLP) ----
    for (int l = 0; l < 3; ++l) {
        elu_zero<<<cdiv((long)NN * 64, 256), 256, 0, stream>>>(emb[l], xin, nbr, (long)NN * 64);
        gin_scatter<<<cdiv((long)EE * 64, 256), 256, 0, stream>>>(xin, src32, dst32, nbr);
        for (long n0 = 0; n0 < NN; n0 += CN) {
            int cn = (int)((NN - n0 < CN) ? (NN - n0) : CN);
            int mpx = cdiv(cdiv(cn, 128), 8);
            gin_combine<<<cdiv((long)cn * 64, 256), 256, 0, stream>>>(xin + n0 * 64, nbr + n0 * 64, hin, (long)cn * 64);
            gemm_bt_bias_elu<<<8 * mpx * 2, 256, 0, stream>>>(hin, g1t + l * 256 * 64, gb1c + l * 256, hg1, cn, 64, 256, mpx, 1);
            gemm_bt_bias_elu<<<8 * mpx * 2, 256, 0, stream>>>(hg1, g2t + l * 256 * 256, gb2c + l * 256, hg2, cn, 256, 256, mpx, 1);
            gemm_bt_f32<<<cdiv(cn, 256), 256, 0, stream>>>(hg2, g3t + l * 64 * 256, gb3c + l * 64, emb[l + 1] + n0 * 64, cn, 256);
        }
    }
    write_out<<<cdiv((long)NN * 64, 256), 256, 0, stream>>>(emb[0], emb[1], emb[2], emb[3], out);
}

// Round 11
// 1445.411 us; speedup vs baseline: 1.0997x; 1.0153x over previous
//
#include <hip/hip_runtime.h>
#include <hip/hip_bf16.h>

// GraphEncoder: NNConv (edge-MLP 16->256->1024->1024 + einsum + scatter) + 3x GINConv.
// R18: 1467us (best). Round-exact grids CONFIRMED: enn-L3 126->87.7us/chunk
// (predicted 84-88), occ 17->19.9. Per-phase cost unchanged (783 TF plateau for
// this structure; schedule surgery 0-for-3 -> frozen).
// R19: consolidation. Budget: ~175us in ~50 dispatch gaps + small fusions.
// (1) add_root_fused: emb0 + xin=bf16(elu) + nbr=0 in one pass (drop l=0
// elu_zero). (2) chunk plan {5x32768, 36160} (tail merged; -4 dispatches; same
// 13 enn-L3 rounds; buffer 167MB guarded, fallback to R18 plan). All GPU kernels
// byte-identical to R18.

#define NN 50000
#define EE 200000

typedef unsigned short u16;
typedef __attribute__((ext_vector_type(8))) short frag8;
typedef __attribute__((ext_vector_type(4))) float f32x4;

__device__ __forceinline__ float bf2f(u16 u) {
    union { unsigned int i; float f; } v; v.i = ((unsigned int)u) << 16; return v.f;
}
__device__ __forceinline__ u16 f2bf(float f) {
    union { float f; unsigned int i; } v; v.f = f;
    return (u16)((v.i + 0x7fffu + ((v.i >> 16) & 1u)) >> 16);
}
__device__ __forceinline__ float eluf(float v) {
    return v > 0.f ? v : __expf(v) - 1.f;
}

// ---------------- float dtype probe: fp32-as-bf16 shows crazy exponents ----------------
__global__ void probe_f32(const u16* __restrict__ raw, int* __restrict__ cnt) {
    int t = threadIdx.x;  // single block of 256
    int c = 0;
    for (int j = t; j < 1024; j += 256) {
        unsigned e = (raw[j] >> 7) & 0xFF;
        if (e >= 0xBF) c++;   // |v| >= 2^64: never in genuine N(0,1)-ish bf16 data
    }
    if (c) atomicAdd(cnt, c);
}

// ---------------- batched bf16 normalize: 16 tensors in one launch ----------------
struct CvtPtrs { const void* src[16]; u16* dst[16]; };
__global__ void cvt_all(CvtPtrs p, const int* __restrict__ cnt) {
    constexpr long L[16] = {800000, 3200000, 4096, 256, 262144, 1024, 1048576, 1024,
                            1024, 64, 49152, 768, 196608, 768, 49152, 192};
    long idx = (long)blockIdx.x * 256 + threadIdx.x;
    const bool isf32 = (*cnt >= 8);
    long base = 0;
    #pragma unroll
    for (int i = 0; i < 16; ++i) {
        if (idx >= base && idx < base + L[i]) {
            long k = idx - base;
            p.dst[i][k] = isf32 ? f2bf(((const float*)p.src[i])[k])
                                : ((const u16*)p.src[i])[k];
        }
        base += L[i];
    }
}

// ---------------- edge_index layout probe + conversion ----------------
__global__ void detect_idx64(const unsigned long long* __restrict__ p, int* __restrict__ flag) {
    long t = (long)blockIdx.x * 256 + threadIdx.x;
    if (t < EE) {
        unsigned long long v = p[t];
        if (v >> 31) atomicOr(flag, 1);   // int32-packed pairs have high bits set
    }
}
__global__ void convert_idx(const void* __restrict__ raw, const int* __restrict__ flag,
                            int* __restrict__ s_out, int* __restrict__ d_out) {
    long t = (long)blockIdx.x * 256 + threadIdx.x;
    if (t >= EE) return;
    if (*flag) {  // int32 layout
        const int* q = (const int*)raw;
        s_out[t] = q[t];
        d_out[t] = q[EE + t];
    } else {      // int64 layout
        const long long* q = (const long long*)raw;
        s_out[t] = (int)q[t];
        d_out[t] = (int)q[EE + t];
    }
}

// ---------------- batched bf16 transpose: 11 jobs [K,N]->[N,K] in one launch ----------
struct TransPtrs { const u16* in[11]; u16* out[11]; };
__global__ void transpose_all(TransPtrs p) {
    constexpr int TK[11] = {256, 1024, 64, 256, 256, 64, 256, 256, 64, 256, 256};
    constexpr int TN[11] = {1024, 1024, 256, 256, 64, 256, 256, 64, 256, 256, 64};
    long idx = (long)blockIdx.x * 256 + threadIdx.x;
    long base = 0;
    #pragma unroll
    for (int i = 0; i < 11; ++i) {
        const long sz = (long)TK[i] * TN[i];
        if (idx >= base && idx < base + sz) {
            long v = idx - base;
            int k = (int)(v / TN[i]);
            int n = (int)(v % TN[i]);
            p.out[i][(long)n * TK[i] + k] = p.in[i][v];
        }
        base += sz;
    }
}

// ---------------- pad attr [E,16] -> [E,32] (zeros in k>=16) ----------------
__global__ void pad_attr(const u16* __restrict__ a16, u16* __restrict__ a32) {
    long idx = (long)blockIdx.x * 256 + threadIdx.x;
    if (idx >= (long)EE * 32) return;
    int k = (int)(idx & 31);
    long e = idx >> 5;
    a32[idx] = (k < 16) ? a16[e * 16 + k] : (u16)0;
}
// w1 [16,256] -> padded BT layout [256][32] (zeros in k>=16)
__global__ void pad_w1t(const u16* __restrict__ w1, u16* __restrict__ w1t32) {
    int idx = blockIdx.x * 256 + threadIdx.x;
    if (idx >= 256 * 32) return;
    int k = idx & 31, n = idx >> 5;
    w1t32[idx] = (k < 16) ? w1[k * 256 + n] : (u16)0;
}

// ---- stage 128x32 bf16 tile via global_load_lds (128^2 path) ----
__device__ __forceinline__ void stage_tile(const u16* g, long row_base, long max_row,
                                           int kstride, int k0, u16* s, int t) {
    int wave = t >> 6;
    #pragma unroll
    for (int j = 0; j < 2; ++j) {
        int c = t + 256 * j;                 // chunk id 0..511 (16B each)
        long r = row_base + (c >> 2);        // 4 chunks per 32-elem row
        if (r > max_row) r = max_row;        // tail clamp (masked at C store)
        const u16* gp = g + r * (long)kstride + k0 + (c & 3) * 8;
        __builtin_amdgcn_global_load_lds(
            (__attribute__((address_space(1))) void*)(void*)gp,
            (__attribute__((address_space(3))) void*)((char*)s + wave * 1024 + j * 4096),
            16, 0, 0);                       // HW writes LDS at base + lane*16
    }
}

// C = ELU(A[M,K] @ BT[N,K]^T + bias), bf16 out. N mult of 128, K mult of 32.
// XCD-swizzled 1D grid. Used for edge-L1 (K=32), GIN g1 (K=64), GIN g2 (K=256).
__global__ __launch_bounds__(256)
void gemm_bt_bias_elu(const u16* __restrict__ A, const u16* __restrict__ BT,
                      const u16* __restrict__ bias, u16* __restrict__ C,
                      int M, int K, int N, int mpx, int lognt) {
    const int bid = blockIdx.x;
    const int xcd = bid & 7;
    const int j = bid >> 3;
    const int m_idx = xcd * mpx + (j >> lognt);
    const int n_idx = j & ((1 << lognt) - 1);
    const int num_m = (M + 127) >> 7;
    if (m_idx >= num_m) return;              // block-uniform; before any barrier

    __shared__ __align__(16) u16 sA[128 * 32];
    __shared__ __align__(16) u16 sB[128 * 32];
    const int t = threadIdx.x;
    const int lane = t & 63;
    const int wave = t >> 6;
    const int wr = wave >> 1, wc = wave & 1;
    const int quad = lane >> 4, l16 = lane & 15;
    const long m0 = (long)m_idx * 128;
    const int n0 = n_idx * 128;

    f32x4 acc[4][4];
    const f32x4 z4 = {0.f, 0.f, 0.f, 0.f};
    #pragma unroll
    for (int mi = 0; mi < 4; ++mi)
        #pragma unroll
        for (int ni = 0; ni < 4; ++ni)
            acc[mi][ni] = z4;

    for (int k0 = 0; k0 < K; k0 += 32) {
        stage_tile(A, m0, (long)M - 1, K, k0, sA, t);
        stage_tile(BT, n0, (long)N - 1, K, k0, sB, t);
        __syncthreads();
        frag8 af[4], bfv[4];
        #pragma unroll
        for (int mi = 0; mi < 4; ++mi)
            af[mi] = *(const frag8*)(sA + (wr * 64 + mi * 16 + l16) * 32 + quad * 8);
        #pragma unroll
        for (int ni = 0; ni < 4; ++ni)
            bfv[ni] = *(const frag8*)(sB + (wc * 64 + ni * 16 + l16) * 32 + quad * 8);
        #pragma unroll
        for (int mi = 0; mi < 4; ++mi)
            #pragma unroll
            for (int ni = 0; ni < 4; ++ni)
                acc[mi][ni] = __builtin_amdgcn_mfma_f32_16x16x32_bf16(af[mi], bfv[ni], acc[mi][ni], 0, 0, 0);
        __syncthreads();
    }

    #pragma unroll
    for (int mi = 0; mi < 4; ++mi) {
        #pragma unroll
        for (int r = 0; r < 4; ++r) {
            long row = m0 + wr * 64 + mi * 16 + quad * 4 + r;  // C/D: row = quad*4+reg
            if (row < M) {
                #pragma unroll
                for (int ni = 0; ni < 4; ++ni) {
                    int col = n0 + wc * 64 + ni * 16 + l16;    // C/D: col = lane&15
                    float v = acc[mi][ni][r] + bf2f(bias[col]);
                    C[row * (long)N + col] = f2bf(eluf(v));
                }
            }
        }
    }
}

// ---------------- 8-phase 256x256 GEMM core (R14 schedule, verified) ----------------
// LDS 128KB = buf{0,1} x {A0,A1,B0,B1} x 16KB; region = 128 rows x 64 k, row=128B,
// swizzle LDS[row][s] = global slot s^(row&7), separable -> folded base pointers.
// Phase: {reads; stage 1 region; [vmcnt(4) @ph4/8]; barrier; setprio; 16 MFMA;
// setprio; barrier}. Race ledger in R12-R14 comments (verified passing).

#define QPHASE(PA0, PA1, PB0, PB1, QM, QN, LDA, LDB, VMW, STREG, SG, SRB, SRM, SCL, SKT) \
  do {                                                                           \
    if (LDA) {                                                                   \
      _Pragma("unroll")                                                          \
      for (int mi = 0; mi < 4; ++mi) {                                           \
        av[mi][0] = *(const frag8*)((PA0) + ((QM) * 4 + mi) * 2048);             \
        av[mi][1] = *(const frag8*)((PA1) + ((QM) * 4 + mi) * 2048);             \
      }                                                                          \
    }                                                                            \
    if ((LDB) >= 0) {                                                            \
      _Pragma("unroll")                                                          \
      for (int ni = 0; ni < 2; ++ni) {                                           \
        bv[(LDB) & 1][ni][0] = *(const frag8*)((PB0) + (((LDB) & 1) * 2 + ni) * 2048); \
        bv[(LDB) & 1][ni][1] = *(const frag8*)((PB1) + (((LDB) & 1) * 2 + ni) * 2048); \
      }                                                                          \
    }                                                                            \
    stage((STREG), (SG), (SRB), (SRM), (SKT), (SCL));                            \
    if (VMW) asm volatile("s_waitcnt vmcnt(4)" ::: "memory");                    \
    __builtin_amdgcn_s_barrier();                                                \
    __builtin_amdgcn_s_setprio(1);                                               \
    _Pragma("unroll")                                                            \
    for (int kk = 0; kk < 2; ++kk) {                                             \
      _Pragma("unroll")                                                          \
      for (int mi = 0; mi < 4; ++mi) {                                           \
        _Pragma("unroll")                                                        \
        for (int ni = 0; ni < 2; ++ni) {                                         \
          acc[(QM) * 4 + mi][(QN) * 2 + ni] =                                    \
              __builtin_amdgcn_mfma_f32_16x16x32_bf16(                           \
                  av[mi][kk], bv[(QN)][ni][kk],                                  \
                  acc[(QM) * 4 + mi][(QN) * 2 + ni], 0, 0, 0);                   \
        }                                                                        \
      }                                                                          \
    }                                                                            \
    __builtin_amdgcn_s_setprio(0);                                               \
    __builtin_amdgcn_s_barrier();                                                \
  } while (0)

__global__ __launch_bounds__(512, 2)
void gemm256p(const u16* __restrict__ A, const u16* __restrict__ BT,
              const u16* __restrict__ bias, u16* __restrict__ C,
              int M, int K, int N, int mpx, int lognt) {
    const int bid = blockIdx.x;
    const int xcd = bid & 7;
    const int j = bid >> 3;
    const int m_idx = xcd * mpx + (j >> lognt);
    const int n_idx = j & ((1 << lognt) - 1);
    const int num_m = (M + 255) >> 8;
    if (m_idx >= num_m) return;              // block-uniform; before any barrier

    __shared__ __align__(16) u16 lds[2][4][8192];  // [buf][A0,A1,B0,B1][16KB]
    const int t = threadIdx.x;
    const int lane = t & 63;
    const int wave = t >> 6;          // 0..7
    const int wm = wave >> 2;         // 0..1 : M half (128 rows)
    const int wn = wave & 3;          // 0..3 : N quarter (64 cols)
    const int quad = lane >> 4, l16 = lane & 15;
    const long m0 = (long)m_idx * 256;
    const long n0 = (long)n_idx * 256;

    // folded LDS read bases (separable swizzle)
    const int aoff0 = l16 * 128 + ((quad ^ (l16 & 3)) << 4) + (((l16 >> 2) & 1) << 6);
    const int aoff1 = aoff0 ^ 64;                       // kk=1 flips byte-bit 6
    const int bex = (wn & 1) * 8192;
    const char* pAX0 = (const char*)&lds[0][wm][0] + aoff0;
    const char* pAX1 = (const char*)&lds[0][wm][0] + aoff1;
    const char* pAY0 = (const char*)&lds[1][wm][0] + aoff0;
    const char* pAY1 = (const char*)&lds[1][wm][0] + aoff1;
    const char* pBX0 = (const char*)&lds[0][2 + (wn >> 1)][0] + aoff0 + bex;
    const char* pBX1 = (const char*)&lds[0][2 + (wn >> 1)][0] + aoff1 + bex;
    const char* pBY0 = (const char*)&lds[1][2 + (wn >> 1)][0] + aoff0 + bex;
    const char* pBY1 = (const char*)&lds[1][2 + (wn >> 1)][0] + aoff1 + bex;

    // staging: chunk ck = wave*2+jj covers 8 rows (1KB); global 16B-slot
    // pre-swizzled g=(lane&7)^((lane>>3)&7) so swizzled read finds slot s^(row&7).
    const int gslot = (((lane & 7) ^ ((lane >> 3) & 7)) << 3);
    const int lane_row = lane >> 3;
    const long lane_go = (long)lane_row * K + gslot;

    auto stage = [&](u16* sreg, const u16* G, long rbase, long rmax, int kt, bool cl) {
        #pragma unroll
        for (int jj = 0; jj < 2; ++jj) {
            const int ck = wave * 2 + jj;
            const u16* gp;
            if (!cl) {
                gp = G + (rbase + ck * 8) * (long)K + ((long)kt << 6) + lane_go;
            } else {
                long r = rbase + ck * 8 + lane_row;
                if (r > rmax) r = rmax;      // tail clamp, masked at C store
                gp = G + r * (long)K + ((long)kt << 6) + gslot;
            }
            __builtin_amdgcn_global_load_lds(
                (__attribute__((address_space(1))) void*)(void*)gp,
                (__attribute__((address_space(3))) void*)((char*)sreg + ck * 1024),
                16, 0, 0);
        }
    };

    f32x4 acc[8][4];
    const f32x4 z4 = {0.f, 0.f, 0.f, 0.f};
    #pragma unroll
    for (int mi = 0; mi < 8; ++mi)
        #pragma unroll
        for (int ni = 0; ni < 4; ++ni)
            acc[mi][ni] = z4;
    frag8 av[4][2];
    frag8 bv[2][2][2];

    const int ntk = K >> 6;          // K multiple of 128 -> ntk even
    const int niter = ntk >> 1;
    const long MM = (long)M - 1, NMX = (long)N - 1;
    const bool aclamp = (m0 + 255) > MM;     // block-uniform

    stage(&lds[0][2][0], BT, n0,       NMX, 0, false);
    stage(&lds[0][3][0], BT, n0 + 128, NMX, 0, false);
    stage(&lds[0][0][0], A,  m0,       MM,  0, aclamp);
    stage(&lds[0][1][0], A,  m0 + 128, MM,  0, aclamp);
    stage(&lds[1][2][0], BT, n0,       NMX, 1, false);
    stage(&lds[1][3][0], BT, n0 + 128, NMX, 1, false);
    asm volatile("s_waitcnt vmcnt(4)" ::: "memory");   // tile0's 8 loads landed
    __builtin_amdgcn_s_barrier();

    for (int it = 0; it < niter; ++it) {
        const int t1k = 2 * it + 1;
        int t2k = 2 * it + 2; if (t2k > ntk - 1) t2k = ntk - 1;
        int t3k = 2 * it + 3; if (t3k > ntk - 1) t3k = ntk - 1;

        QPHASE(pAX0, pAX1, pBX0, pBX1, 0, 0, 1,  0, 0, &lds[1][0][0], A,  m0,       MM,  aclamp, t1k);
        QPHASE(pAX0, pAX1, pBX0, pBX1, 0, 1, 0,  1, 0, &lds[1][1][0], A,  m0 + 128, MM,  aclamp, t1k);
        QPHASE(pAX0, pAX1, pBX0, pBX1, 1, 0, 1, -1, 0, &lds[0][2][0], BT, n0,       NMX, false,  t2k);
        QPHASE(pAX0, pAX1, pBX0, pBX1, 1, 1, 0, -1, 1, &lds[0][3][0], BT, n0 + 128, NMX, false,  t2k);
        QPHASE(pAY0, pAY1, pBY0, pBY1, 0, 0, 1,  0, 0, &lds[0][0][0], A,  m0,       MM,  aclamp, t2k);
        QPHASE(pAY0, pAY1, pBY0, pBY1, 0, 1, 0,  1, 0, &lds[0][1][0], A,  m0 + 128, MM,  aclamp, t2k);
        QPHASE(pAY0, pAY1, pBY0, pBY1, 1, 0, 1, -1, 0, &lds[1][2][0], BT, n0,       NMX, false,  t3k);
        QPHASE(pAY0, pAY1, pBY0, pBY1, 1, 1, 0, -1, 1, &lds[1][3][0], BT, n0 + 128, NMX, false,  t3k);
    }
    asm volatile("s_waitcnt vmcnt(0)" ::: "memory");   // drain leftover stages

    #pragma unroll
    for (int mi = 0; mi < 8; ++mi) {
        #pragma unroll
        for (int r = 0; r < 4; ++r) {
            long row = m0 + wm * 128 + mi * 16 + quad * 4 + r;   // C/D: row = quad*4+reg
            if (row < M) {
                #pragma unroll
                for (int ni = 0; ni < 4; ++ni) {
                    long col = n0 + wn * 64 + ni * 16 + l16;     // C/D: col = lane&15
                    float v = acc[mi][ni][r] + bf2f(bias[col]);
                    C[row * (long)N + col] = f2bf(eluf(v));
                }
            }
        }
    }
}

// C[M,64] fp32 = A[M,K] @ BT[64,K]^T + bias (no ELU). M-tile 256, N=64, K mult of 32.
__global__ __launch_bounds__(256)
void gemm_bt_f32(const u16* __restrict__ A, const u16* __restrict__ BT,
                 const u16* __restrict__ bias, float* __restrict__ C,
                 int M, int K) {
    __shared__ __align__(16) u16 sA[256 * 32];
    __shared__ __align__(16) u16 sB[64 * 32];
    const int t = threadIdx.x;
    const int lane = t & 63;
    const int wave = t >> 6;
    const int quad = lane >> 4, l16 = lane & 15;
    const long m0 = (long)blockIdx.x * 256;

    f32x4 acc[4][4];
    const f32x4 z4 = {0.f, 0.f, 0.f, 0.f};
    #pragma unroll
    for (int mi = 0; mi < 4; ++mi)
        #pragma unroll
        for (int ni = 0; ni < 4; ++ni)
            acc[mi][ni] = z4;

    for (int k0 = 0; k0 < K; k0 += 32) {
        #pragma unroll
        for (int j = 0; j < 4; ++j) {
            int c = t + 256 * j;
            long r = m0 + (c >> 2);
            if (r > (long)M - 1) r = (long)M - 1;
            const u16* gp = A + r * (long)K + k0 + (c & 3) * 8;
            __builtin_amdgcn_global_load_lds(
                (__attribute__((address_space(1))) void*)(void*)gp,
                (__attribute__((address_space(3))) void*)((char*)sA + wave * 1024 + j * 4096),
                16, 0, 0);
        }
        {
            int c = t;
            const u16* gp = BT + (long)(c >> 2) * K + k0 + (c & 3) * 8;
            __builtin_amdgcn_global_load_lds(
                (__attribute__((address_space(1))) void*)(void*)gp,
                (__attribute__((address_space(3))) void*)((char*)sB + wave * 1024),
                16, 0, 0);
        }
        __syncthreads();
        frag8 af[4], bfv[4];
        #pragma unroll
        for (int mi = 0; mi < 4; ++mi)
            af[mi] = *(const frag8*)(sA + (wave * 64 + mi * 16 + l16) * 32 + quad * 8);
        #pragma unroll
        for (int ni = 0; ni < 4; ++ni)
            bfv[ni] = *(const frag8*)(sB + (ni * 16 + l16) * 32 + quad * 8);
        #pragma unroll
        for (int mi = 0; mi < 4; ++mi)
            #pragma unroll
            for (int ni = 0; ni < 4; ++ni)
                acc[mi][ni] = __builtin_amdgcn_mfma_f32_16x16x32_bf16(af[mi], bfv[ni], acc[mi][ni], 0, 0, 0);
        __syncthreads();
    }

    #pragma unroll
    for (int mi = 0; mi < 4; ++mi) {
        #pragma unroll
        for (int r = 0; r < 4; ++r) {
            long row = m0 + wave * 64 + mi * 16 + quad * 4 + r;
            if (row < M) {
                #pragma unroll
                for (int ni = 0; ni < 4; ++ni) {
                    int col = ni * 16 + l16;
                    C[row * 64 + col] = acc[mi][ni][r] + bf2f(bias[col]);
                }
            }
        }
    }
}

// msg[e,o] = sum_i x[src[e],i] * we[e, i*64+o]; atomicAdd into agg[dst[e],o]
__global__ void nnconv_msg(const u16* __restrict__ we, const u16* __restrict__ x,
                           const int* __restrict__ src, const int* __restrict__ dst,
                           float* __restrict__ agg, int ce) {
    long idx = (long)blockIdx.x * 256 + threadIdx.x;
    if (idx >= (long)ce * 64) return;
    int o = (int)(idx & 63);
    long e = idx >> 6;
    const u16* wr = we + e * 1024;
    const u16* xr = x + (long)src[e] * 16;
    float v = 0.f;
    #pragma unroll
    for (int i = 0; i < 16; ++i)
        v += bf2f(xr[i]) * bf2f(wr[i * 64 + o]);
    atomicAdd(&agg[(long)dst[e] * 64 + o], v);
}

// ---- fused: x_cur = x@root_w + root_b + agg (in-place on agg=emb0);
// ALSO emit xin = bf16(elu(x_cur)) and nbr = 0 for GIN layer 0 ----
__global__ void add_root_fused(const u16* __restrict__ x, const u16* __restrict__ rw,
                               const u16* __restrict__ rb, float* __restrict__ xcur,
                               u16* __restrict__ xin, float* __restrict__ nbr) {
    long idx = (long)blockIdx.x * 256 + threadIdx.x;
    if (idx >= (long)NN * 64) return;
    int d = (int)(idx & 63);
    long n = idx >> 6;
    float v = bf2f(rb[d]);
    #pragma unroll
    for (int i = 0; i < 16; ++i)
        v += bf2f(x[n * 16 + i]) * bf2f(rw[i * 64 + d]);
    float total = xcur[idx] + v;
    xcur[idx] = total;
    xin[idx] = f2bf(eluf(total));
    nbr[idx] = 0.f;
}

// elu to bf16 AND zero the nbr accumulator (layers 1..2)
__global__ void elu_zero(const float* __restrict__ in, u16* __restrict__ o,
                         float* __restrict__ nbr, long n) {
    long idx = (long)blockIdx.x * 256 + threadIdx.x;
    if (idx < n) { o[idx] = f2bf(eluf(in[idx])); nbr[idx] = 0.f; }
}

__global__ void gin_scatter(const u16* __restrict__ xin, const int* __restrict__ src,
                            const int* __restrict__ dst, float* __restrict__ nbr) {
    long idx = (long)blockIdx.x * 256 + threadIdx.x;
    if (idx >= (long)EE * 64) return;
    int d = (int)(idx & 63);
    long e = idx >> 6;
    atomicAdd(&nbr[(long)dst[e] * 64 + d], bf2f(xin[(long)src[e] * 64 + d]));
}

__global__ void gin_combine(const u16* __restrict__ xin, const float* __restrict__ nbr,
                            u16* __restrict__ hin, long n) {
    long idx = (long)blockIdx.x * 256 + threadIdx.x;
    if (idx < n) hin[idx] = f2bf(bf2f(xin[idx]) + nbr[idx]);
}

// out[n,d,l] = emb_l[n*64+d] -- one float4 per (n,d), fully coalesced
__global__ void write_out(const float* __restrict__ e0, const float* __restrict__ e1,
                          const float* __restrict__ e2, const float* __restrict__ e3,
                          float* __restrict__ out) {
    long idx = (long)blockIdx.x * 256 + threadIdx.x;
    if (idx >= (long)NN * 64) return;
    float4 v = {e0[idx], e1[idx], e2[idx], e3[idx]};
    *(float4*)(out + idx * 4) = v;
}

extern "C" void kernel_launch(void* const* d_in, const int* in_sizes, int n_in,
                              void* d_out, int out_size, void* d_ws, size_t ws_size,
                              hipStream_t stream) {
    (void)in_sizes; (void)n_in; (void)out_size;
    const void* eidx = d_in[1];
    float* out = (float*)d_out;   // reference output dtype = float32

    char* ws = (char*)d_ws;
    size_t off = 0;
    auto alloc = [&](size_t bytes) {
        char* p = ws + off;
        off += (bytes + 255) & ~(size_t)255;
        return p;
    };
    // ---- persistent ----
    int* src32 = (int*)alloc((size_t)EE * 4);
    int* dst32 = (int*)alloc((size_t)EE * 4);
    int* flag  = (int*)alloc(256);
    int* cnt   = (int*)alloc(256);
    const int cv_idx[16] = {0, 2, 3, 4, 5, 6, 7, 8, 9, 10, 11, 12, 13, 14, 15, 16};
    const long cv_n[16]  = {800000, 3200000, 4096, 256, 262144, 1024, 1048576, 1024,
                            1024, 64, 49152, 768, 196608, 768, 49152, 192};
    u16* cv[16];
    for (int i = 0; i < 16; ++i) cv[i] = (u16*)alloc((size_t)cv_n[i] * 2);
    u16 *xc = cv[0], *eac = cv[1], *w1c = cv[2], *b1c = cv[3], *w2c = cv[4], *b2c = cv[5],
        *w3c = cv[6], *b3c = cv[7], *rwc = cv[8], *rbc = cv[9],
        *g1c = cv[10], *gb1c = cv[11], *g2c = cv[12], *gb2c = cv[13], *g3c = cv[14], *gb3c = cv[15];
    u16* w2t = (u16*)alloc((size_t)1024 * 256 * 2);
    u16* w3t = (u16*)alloc((size_t)1024 * 1024 * 2);
    u16* g1t = (u16*)alloc((size_t)3 * 256 * 64 * 2);
    u16* g2t = (u16*)alloc((size_t)3 * 256 * 256 * 2);
    u16* g3t = (u16*)alloc((size_t)3 * 64 * 256 * 2);
    u16* attr32 = (u16*)alloc((size_t)EE * 32 * 2);   // padded edge_attr, K=32
    u16* w1t32  = (u16*)alloc((size_t)256 * 32 * 2);  // padded w1^T [256][32]
    // per-layer node embeddings, fp32 [N,64]; emb[0] doubles as agg/x_cur
    float* emb[4];
    for (int l = 0; l < 4; ++l) emb[l] = (float*)alloc((size_t)NN * 64 * 4);
    float* agg = emb[0];
    char* scratch = (char*)alloc(0);
    size_t avail = (ws_size > off + 4096) ? (ws_size - off - 4096) : 0;

    // ---- NNConv edge-chunk plan: h1c (512 B/e) + h2c (2048 B/e) + wec (2048 B/e) ----
    // Round-exact grids (R18-confirmed): full chunks of 32768 (grid 512 = 2 rounds,
    // num_m 128 = 8x16 exact). Tail merged into the last chunk when buffers allow.
    long CEBUF;                 // buffer sizing (max chunk)
    long plan[8]; int nplan;
    if (avail >= 36160L * 4608) {
        CEBUF = 36160;          // {5 x 32768, 36160} -> 24 dispatches, 13 L3-rounds
        nplan = 6;
        for (int i = 0; i < 5; ++i) plan[i] = 32768;
        plan[5] = 36160;
    } else if (avail >= 32768L * 4608) {
        CEBUF = 32768;          // {6 x 32768, 3392}  (R18 plan)
        nplan = 7;
        for (int i = 0; i < 6; ++i) plan[i] = 32768;
        plan[6] = 3392;
    } else {                    // fallback: dynamic uniform chunks
        CEBUF = (long)(avail / 4608) & ~255L;
        if (CEBUF < 256) CEBUF = 256;
        nplan = 0;
        long rem = EE;
        while (rem > 0 && nplan < 8) {
            long c = rem < CEBUF ? rem : CEBUF;
            plan[nplan++] = c;
            rem -= c;
        }
    }
    u16* h1c = (u16*)scratch;
    u16* h2c = (u16*)(scratch + (size_t)CEBUF * 512);
    u16* wec = (u16*)(scratch + (size_t)CEBUF * 2560);

    // ---- GIN node-chunk: nbr+xin fixed (19.2MB) + 1152 B/node ----
    long gin_fixed = (long)NN * 64 * 4 + (long)NN * 64 * 2;
    long gin_avail = (long)avail - gin_fixed;
    if (gin_avail < 0) gin_avail = 0;
    long CN = (gin_avail / 1152) & ~255L;
    if (CN < 256) CN = 256;
    if (CN > 50176) CN = 50176;
    float* nbr = (float*)scratch;
    u16* xin   = (u16*)(scratch + (size_t)NN * 64 * 4);
    u16* hin   = (u16*)(scratch + gin_fixed);
    u16* hg1   = hin + (size_t)CN * 64;
    u16* hg2   = hg1 + (size_t)CN * 256;

    auto cdiv = [](long a, long b) { return (unsigned)((a + b - 1) / b); };

    // dtype probe on x, then normalize all float inputs to bf16 (ONE batched launch)
    hipMemsetAsync(cnt, 0, 4, stream);
    probe_f32<<<1, 256, 0, stream>>>((const u16*)d_in[0], cnt);
    {
        CvtPtrs cp;
        for (int i = 0; i < 16; ++i) { cp.src[i] = d_in[cv_idx[i]]; cp.dst[i] = cv[i]; }
        long total = 0;
        for (int i = 0; i < 16; ++i) total += cv_n[i];
        cvt_all<<<cdiv(total, 256), 256, 0, stream>>>(cp, cnt);
    }

    // edge_index conversion (layout-robust)
    hipMemsetAsync(flag, 0, 4, stream);
    detect_idx64<<<cdiv(EE, 256), 256, 0, stream>>>((const unsigned long long*)eidx, flag);
    convert_idx<<<cdiv(EE, 256), 256, 0, stream>>>(eidx, flag, src32, dst32);

    // weight transposes [K,N] -> [N,K] (ONE batched launch; order matches TK/TN tables)
    {
        TransPtrs tp;
        tp.in[0] = w2c;  tp.out[0] = w2t;
        tp.in[1] = w3c;  tp.out[1] = w3t;
        for (int l = 0; l < 3; ++l) {
            tp.in[2 + 3 * l] = g1c + l * 64 * 256;   tp.out[2 + 3 * l] = g1t + l * 256 * 64;
            tp.in[3 + 3 * l] = g2c + l * 256 * 256;  tp.out[3 + 3 * l] = g2t + l * 256 * 256;
            tp.in[4 + 3 * l] = g3c + l * 256 * 64;   tp.out[4 + 3 * l] = g3t + l * 64 * 256;
        }
        long total = 262144 + 1048576 + 3 * (16384 + 65536 + 16384);
        transpose_all<<<cdiv(total, 256), 256, 0, stream>>>(tp);
    }
    // pad attr K=16 -> K=32 (once) and w1 -> padded BT [256][32]
    pad_attr<<<cdiv((long)EE * 32, 256), 256, 0, stream>>>(eac, attr32);
    pad_w1t<<<cdiv(256 * 32, 256), 256, 0, stream>>>(w1c, w1t32);

    // ---- NNConv (edge-chunked) ----
    hipMemsetAsync(agg, 0, (size_t)NN * 64 * 4, stream);
    {
        long e0 = 0;
        for (int c = 0; c < nplan; ++c) {
            int ce = (int)plan[c];
            int mpx  = cdiv(cdiv(ce, 128), 8);
            int mpx2 = cdiv(cdiv(ce, 256), 8);
            gemm_bt_bias_elu<<<8 * mpx * 2, 256, 0, stream>>>(attr32 + e0 * 32, w1t32, b1c, h1c, ce, 32, 256, mpx, 1);
            gemm256p<<<8 * mpx2 * 4, 512, 0, stream>>>(h1c, w2t, b2c, h2c, ce, 256, 1024, mpx2, 2);
            gemm256p<<<8 * mpx2 * 4, 512, 0, stream>>>(h2c, w3t, b3c, wec, ce, 1024, 1024, mpx2, 2);
            nnconv_msg<<<cdiv((long)ce * 64, 256), 256, 0, stream>>>(wec, xc, src32 + e0, dst32 + e0, agg, ce);
            e0 += ce;
        }
    }
    // fused: emb0 = x@rw + b + agg; xin = bf16(elu(emb0)); nbr = 0  (layer-0 prep)
    add_root_fused<<<cdiv((long)NN * 64, 256), 256, 0, stream>>>(xc, rwc, rbc, agg, xin, nbr);

    // ---- 3x GINConv (node-chunked MLP) ----
    for (int l = 0; l < 3; ++l) {
        if (l > 0)
            elu_zero<<<cdiv((long)NN * 64, 256), 256, 0, stream>>>(emb[l], xin, nbr, (long)NN * 64);
        gin_scatter<<<cdiv((long)EE * 64, 256), 256, 0, stream>>>(xin, src32, dst32, nbr);
        for (long n0 = 0; n0 < NN; n0 += CN) {
            int cn = (int)((NN - n0 < CN) ? (NN - n0) : CN);
            int mpx = cdiv(cdiv(cn, 128), 8);
            gin_combine<<<cdiv((long)cn * 64, 256), 256, 0, stream>>>(xin + n0 * 64, nbr + n0 * 64, hin, (long)cn * 64);
            gemm_bt_bias_elu<<<8 * mpx * 2, 256, 0, stream>>>(hin, g1t + l * 256 * 64, gb1c + l * 256, hg1, cn, 64, 256, mpx, 1);
            gemm_bt_bias_elu<<<8 * mpx * 2, 256, 0, stream>>>(hg1, g2t + l * 256 * 256, gb2c + l * 256, hg2, cn, 256, 256, mpx, 1);
            gemm_bt_f32<<<cdiv(cn, 256), 256, 0, stream>>>(hg2, g3t + l * 64 * 256, gb3c + l * 64, emb[l + 1] + n0 * 64, cn, 256);
        }
    }
    write_out<<<cdiv((long)NN * 64, 256), 256, 0, stream>>>(emb[0], emb[1], emb[2], emb[3], out);
}

// Round 12
// 1444.725 us; speedup vs baseline: 1.1002x; 1.0005x over previous
//
#include <hip/hip_runtime.h>
#include <hip/hip_bf16.h>

// GraphEncoder: NNConv (edge-MLP 16->256->1024->1024 + einsum + scatter) + 3x GINConv.
// R19: 1445us (best). Merged-tail chunk = 120us = 2.74 round-equiv; enn-L3 at its
// integral round floor (782 m-tiles -> 12.22 min, 13 actual). Gap model ~4-5us per
// removed dispatch confirmed.
// R20: GIN glue fusion. (1) gemm_bt_g1: A-staging computes hin=bf16(xin+nbr) in
// regs + ds_write_b128 to the same linear LDS addr gload_lds used (byte (t+256j)*16)
// -> kills gin_combine + hin buffer. (2) gemm_bt_f32 epilogue also emits
// xin=bf16(elu(v)) and nbr=0 (emit flag; off for last layer) -> kills both
// elu_zero. Chunk-disjoint xin/nbr writes audited. enn path + gemm256p + chunk
// plan byte-identical to R19.

#define NN 50000
#define EE 200000

typedef unsigned short u16;
typedef __attribute__((ext_vector_type(8))) short frag8;
typedef __attribute__((ext_vector_type(4))) float f32x4;

__device__ __forceinline__ float bf2f(u16 u) {
    union { unsigned int i; float f; } v; v.i = ((unsigned int)u) << 16; return v.f;
}
__device__ __forceinline__ u16 f2bf(float f) {
    union { float f; unsigned int i; } v; v.f = f;
    return (u16)((v.i + 0x7fffu + ((v.i >> 16) & 1u)) >> 16);
}
__device__ __forceinline__ float eluf(float v) {
    return v > 0.f ? v : __expf(v) - 1.f;
}

// ---------------- float dtype probe: fp32-as-bf16 shows crazy exponents ----------------
__global__ void probe_f32(const u16* __restrict__ raw, int* __restrict__ cnt) {
    int t = threadIdx.x;  // single block of 256
    int c = 0;
    for (int j = t; j < 1024; j += 256) {
        unsigned e = (raw[j] >> 7) & 0xFF;
        if (e >= 0xBF) c++;   // |v| >= 2^64: never in genuine N(0,1)-ish bf16 data
    }
    if (c) atomicAdd(cnt, c);
}

// ---------------- batched bf16 normalize: 16 tensors in one launch ----------------
struct CvtPtrs { const void* src[16]; u16* dst[16]; };
__global__ void cvt_all(CvtPtrs p, const int* __restrict__ cnt) {
    constexpr long L[16] = {800000, 3200000, 4096, 256, 262144, 1024, 1048576, 1024,
                            1024, 64, 49152, 768, 196608, 768, 49152, 192};
    long idx = (long)blockIdx.x * 256 + threadIdx.x;
    const bool isf32 = (*cnt >= 8);
    long base = 0;
    #pragma unroll
    for (int i = 0; i < 16; ++i) {
        if (idx >= base && idx < base + L[i]) {
            long k = idx - base;
            p.dst[i][k] = isf32 ? f2bf(((const float*)p.src[i])[k])
                                : ((const u16*)p.src[i])[k];
        }
        base += L[i];
    }
}

// ---------------- edge_index layout probe + conversion ----------------
__global__ void detect_idx64(const unsigned long long* __restrict__ p, int* __restrict__ flag) {
    long t = (long)blockIdx.x * 256 + threadIdx.x;
    if (t < EE) {
        unsigned long long v = p[t];
        if (v >> 31) atomicOr(flag, 1);   // int32-packed pairs have high bits set
    }
}
__global__ void convert_idx(const void* __restrict__ raw, const int* __restrict__ flag,
                            int* __restrict__ s_out, int* __restrict__ d_out) {
    long t = (long)blockIdx.x * 256 + threadIdx.x;
    if (t >= EE) return;
    if (*flag) {  // int32 layout
        const int* q = (const int*)raw;
        s_out[t] = q[t];
        d_out[t] = q[EE + t];
    } else {      // int64 layout
        const long long* q = (const long long*)raw;
        s_out[t] = (int)q[t];
        d_out[t] = (int)q[EE + t];
    }
}

// ---------------- batched bf16 transpose: 11 jobs [K,N]->[N,K] in one launch ----------
struct TransPtrs { const u16* in[11]; u16* out[11]; };
__global__ void transpose_all(TransPtrs p) {
    constexpr int TK[11] = {256, 1024, 64, 256, 256, 64, 256, 256, 64, 256, 256};
    constexpr int TN[11] = {1024, 1024, 256, 256, 64, 256, 256, 64, 256, 256, 64};
    long idx = (long)blockIdx.x * 256 + threadIdx.x;
    long base = 0;
    #pragma unroll
    for (int i = 0; i < 11; ++i) {
        const long sz = (long)TK[i] * TN[i];
        if (idx >= base && idx < base + sz) {
            long v = idx - base;
            int k = (int)(v / TN[i]);
            int n = (int)(v % TN[i]);
            p.out[i][(long)n * TK[i] + k] = p.in[i][v];
        }
        base += sz;
    }
}

// ---------------- pad attr [E,16] -> [E,32] (zeros in k>=16) ----------------
__global__ void pad_attr(const u16* __restrict__ a16, u16* __restrict__ a32) {
    long idx = (long)blockIdx.x * 256 + threadIdx.x;
    if (idx >= (long)EE * 32) return;
    int k = (int)(idx & 31);
    long e = idx >> 5;
    a32[idx] = (k < 16) ? a16[e * 16 + k] : (u16)0;
}
// w1 [16,256] -> padded BT layout [256][32] (zeros in k>=16)
__global__ void pad_w1t(const u16* __restrict__ w1, u16* __restrict__ w1t32) {
    int idx = blockIdx.x * 256 + threadIdx.x;
    if (idx >= 256 * 32) return;
    int k = idx & 31, n = idx >> 5;
    w1t32[idx] = (k < 16) ? w1[k * 256 + n] : (u16)0;
}

// ---- stage 128x32 bf16 tile via global_load_lds (128^2 path) ----
__device__ __forceinline__ void stage_tile(const u16* g, long row_base, long max_row,
                                           int kstride, int k0, u16* s, int t) {
    int wave = t >> 6;
    #pragma unroll
    for (int j = 0; j < 2; ++j) {
        int c = t + 256 * j;                 // chunk id 0..511 (16B each)
        long r = row_base + (c >> 2);        // 4 chunks per 32-elem row
        if (r > max_row) r = max_row;        // tail clamp (masked at C store)
        const u16* gp = g + r * (long)kstride + k0 + (c & 3) * 8;
        __builtin_amdgcn_global_load_lds(
            (__attribute__((address_space(1))) void*)(void*)gp,
            (__attribute__((address_space(3))) void*)((char*)s + wave * 1024 + j * 4096),
            16, 0, 0);                       // HW writes LDS at base + lane*16
    }
}

// C = ELU(A[M,K] @ BT[N,K]^T + bias), bf16 out. N mult of 128, K mult of 32.
// XCD-swizzled 1D grid. Used for edge-L1 (K=32) and GIN g2 (K=256).
__global__ __launch_bounds__(256)
void gemm_bt_bias_elu(const u16* __restrict__ A, const u16* __restrict__ BT,
                      const u16* __restrict__ bias, u16* __restrict__ C,
                      int M, int K, int N, int mpx, int lognt) {
    const int bid = blockIdx.x;
    const int xcd = bid & 7;
    const int j = bid >> 3;
    const int m_idx = xcd * mpx + (j >> lognt);
    const int n_idx = j & ((1 << lognt) - 1);
    const int num_m = (M + 127) >> 7;
    if (m_idx >= num_m) return;              // block-uniform; before any barrier

    __shared__ __align__(16) u16 sA[128 * 32];
    __shared__ __align__(16) u16 sB[128 * 32];
    const int t = threadIdx.x;
    const int lane = t & 63;
    const int wave = t >> 6;
    const int wr = wave >> 1, wc = wave & 1;
    const int quad = lane >> 4, l16 = lane & 15;
    const long m0 = (long)m_idx * 128;
    const int n0 = n_idx * 128;

    f32x4 acc[4][4];
    const f32x4 z4 = {0.f, 0.f, 0.f, 0.f};
    #pragma unroll
    for (int mi = 0; mi < 4; ++mi)
        #pragma unroll
        for (int ni = 0; ni < 4; ++ni)
            acc[mi][ni] = z4;

    for (int k0 = 0; k0 < K; k0 += 32) {
        stage_tile(A, m0, (long)M - 1, K, k0, sA, t);
        stage_tile(BT, n0, (long)N - 1, K, k0, sB, t);
        __syncthreads();
        frag8 af[4], bfv[4];
        #pragma unroll
        for (int mi = 0; mi < 4; ++mi)
            af[mi] = *(const frag8*)(sA + (wr * 64 + mi * 16 + l16) * 32 + quad * 8);
        #pragma unroll
        for (int ni = 0; ni < 4; ++ni)
            bfv[ni] = *(const frag8*)(sB + (wc * 64 + ni * 16 + l16) * 32 + quad * 8);
        #pragma unroll
        for (int mi = 0; mi < 4; ++mi)
            #pragma unroll
            for (int ni = 0; ni < 4; ++ni)
                acc[mi][ni] = __builtin_amdgcn_mfma_f32_16x16x32_bf16(af[mi], bfv[ni], acc[mi][ni], 0, 0, 0);
        __syncthreads();
    }

    #pragma unroll
    for (int mi = 0; mi < 4; ++mi) {
        #pragma unroll
        for (int r = 0; r < 4; ++r) {
            long row = m0 + wr * 64 + mi * 16 + quad * 4 + r;  // C/D: row = quad*4+reg
            if (row < M) {
                #pragma unroll
                for (int ni = 0; ni < 4; ++ni) {
                    int col = n0 + wc * 64 + ni * 16 + l16;    // C/D: col = lane&15
                    float v = acc[mi][ni][r] + bf2f(bias[col]);
                    C[row * (long)N + col] = f2bf(eluf(v));
                }
            }
        }
    }
}

// GIN g1: C = ELU((xin + nbr)[M,K] @ BT[N,K]^T + bias); A computed on the fly
// (hin never materialized). A written via ds_write_b128 to the SAME linear LDS
// address global_load_lds would use (byte (t+256j)*16) -> reads unchanged.
__global__ __launch_bounds__(256)
void gemm_bt_g1(const u16* __restrict__ xin, const float* __restrict__ nbr,
                const u16* __restrict__ BT, const u16* __restrict__ bias,
                u16* __restrict__ C, int M, int K, int N, int mpx, int lognt) {
    const int bid = blockIdx.x;
    const int xcd = bid & 7;
    const int j = bid >> 3;
    const int m_idx = xcd * mpx + (j >> lognt);
    const int n_idx = j & ((1 << lognt) - 1);
    const int num_m = (M + 127) >> 7;
    if (m_idx >= num_m) return;              // block-uniform; before any barrier

    __shared__ __align__(16) u16 sA[128 * 32];
    __shared__ __align__(16) u16 sB[128 * 32];
    const int t = threadIdx.x;
    const int lane = t & 63;
    const int wave = t >> 6;
    const int wr = wave >> 1, wc = wave & 1;
    const int quad = lane >> 4, l16 = lane & 15;
    const long m0 = (long)m_idx * 128;
    const int n0 = n_idx * 128;
    const long MM = (long)M - 1;

    f32x4 acc[4][4];
    const f32x4 z4 = {0.f, 0.f, 0.f, 0.f};
    #pragma unroll
    for (int mi = 0; mi < 4; ++mi)
        #pragma unroll
        for (int ni = 0; ni < 4; ++ni)
            acc[mi][ni] = z4;

    for (int k0 = 0; k0 < K; k0 += 32) {
        // A-tile: hin = bf16(xin + nbr), computed in regs, ds_write to linear slot
        #pragma unroll
        for (int jj = 0; jj < 2; ++jj) {
            int c = t + 256 * jj;
            long r = m0 + (c >> 2);
            if (r > MM) r = MM;              // tail clamp (masked at C store)
            long e = r * (long)K + k0 + (c & 3) * 8;   // K==64 for g1; col<64
            frag8 xv = *(const frag8*)(xin + e);
            float4 na = *(const float4*)(nbr + e);
            float4 nb = *(const float4*)(nbr + e + 4);
            frag8 o;
            #pragma unroll
            for (int kq = 0; kq < 8; ++kq) {
                float nv = (kq < 4) ? ((const float*)&na)[kq] : ((const float*)&nb)[kq - 4];
                o[kq] = (short)f2bf(bf2f((u16)xv[kq]) + nv);
            }
            *(frag8*)((char*)sA + (size_t)(t + 256 * jj) * 16) = o;
        }
        stage_tile(BT, n0, (long)N - 1, K, k0, sB, t);
        __syncthreads();
        frag8 af[4], bfv[4];
        #pragma unroll
        for (int mi = 0; mi < 4; ++mi)
            af[mi] = *(const frag8*)(sA + (wr * 64 + mi * 16 + l16) * 32 + quad * 8);
        #pragma unroll
        for (int ni = 0; ni < 4; ++ni)
            bfv[ni] = *(const frag8*)(sB + (wc * 64 + ni * 16 + l16) * 32 + quad * 8);
        #pragma unroll
        for (int mi = 0; mi < 4; ++mi)
            #pragma unroll
            for (int ni = 0; ni < 4; ++ni)
                acc[mi][ni] = __builtin_amdgcn_mfma_f32_16x16x32_bf16(af[mi], bfv[ni], acc[mi][ni], 0, 0, 0);
        __syncthreads();
    }

    #pragma unroll
    for (int mi = 0; mi < 4; ++mi) {
        #pragma unroll
        for (int r = 0; r < 4; ++r) {
            long row = m0 + wr * 64 + mi * 16 + quad * 4 + r;
            if (row < M) {
                #pragma unroll
                for (int ni = 0; ni < 4; ++ni) {
                    int col = n0 + wc * 64 + ni * 16 + l16;
                    float v = acc[mi][ni][r] + bf2f(bias[col]);
                    C[row * (long)N + col] = f2bf(eluf(v));
                }
            }
        }
    }
}

// ---------------- 8-phase 256x256 GEMM core (R14 schedule, verified) ----------------
// LDS 128KB = buf{0,1} x {A0,A1,B0,B1} x 16KB; region = 128 rows x 64 k, row=128B,
// swizzle LDS[row][s] = global slot s^(row&7), separable -> folded base pointers.
// Phase: {reads; stage 1 region; [vmcnt(4) @ph4/8]; barrier; setprio; 16 MFMA;
// setprio; barrier}. Race ledger in R12-R14 comments (verified passing).

#define QPHASE(PA0, PA1, PB0, PB1, QM, QN, LDA, LDB, VMW, STREG, SG, SRB, SRM, SCL, SKT) \
  do {                                                                           \
    if (LDA) {                                                                   \
      _Pragma("unroll")                                                          \
      for (int mi = 0; mi < 4; ++mi) {                                           \
        av[mi][0] = *(const frag8*)((PA0) + ((QM) * 4 + mi) * 2048);             \
        av[mi][1] = *(const frag8*)((PA1) + ((QM) * 4 + mi) * 2048);             \
      }                                                                          \
    }                                                                            \
    if ((LDB) >= 0) {                                                            \
      _Pragma("unroll")                                                          \
      for (int ni = 0; ni < 2; ++ni) {                                           \
        bv[(LDB) & 1][ni][0] = *(const frag8*)((PB0) + (((LDB) & 1) * 2 + ni) * 2048); \
        bv[(LDB) & 1][ni][1] = *(const frag8*)((PB1) + (((LDB) & 1) * 2 + ni) * 2048); \
      }                                                                          \
    }                                                                            \
    stage((STREG), (SG), (SRB), (SRM), (SKT), (SCL));                            \
    if (VMW) asm volatile("s_waitcnt vmcnt(4)" ::: "memory");                    \
    __builtin_amdgcn_s_barrier();                                                \
    __builtin_amdgcn_s_setprio(1);                                               \
    _Pragma("unroll")                                                            \
    for (int kk = 0; kk < 2; ++kk) {                                             \
      _Pragma("unroll")                                                          \
      for (int mi = 0; mi < 4; ++mi) {                                           \
        _Pragma("unroll")                                                        \
        for (int ni = 0; ni < 2; ++ni) {                                         \
          acc[(QM) * 4 + mi][(QN) * 2 + ni] =                                    \
              __builtin_amdgcn_mfma_f32_16x16x32_bf16(                           \
                  av[mi][kk], bv[(QN)][ni][kk],                                  \
                  acc[(QM) * 4 + mi][(QN) * 2 + ni], 0, 0, 0);                   \
        }                                                                        \
      }                                                                          \
    }                                                                            \
    __builtin_amdgcn_s_setprio(0);                                               \
    __builtin_amdgcn_s_barrier();                                                \
  } while (0)

__global__ __launch_bounds__(512, 2)
void gemm256p(const u16* __restrict__ A, const u16* __restrict__ BT,
              const u16* __restrict__ bias, u16* __restrict__ C,
              int M, int K, int N, int mpx, int lognt) {
    const int bid = blockIdx.x;
    const int xcd = bid & 7;
    const int j = bid >> 3;
    const int m_idx = xcd * mpx + (j >> lognt);
    const int n_idx = j & ((1 << lognt) - 1);
    const int num_m = (M + 255) >> 8;
    if (m_idx >= num_m) return;              // block-uniform; before any barrier

    __shared__ __align__(16) u16 lds[2][4][8192];  // [buf][A0,A1,B0,B1][16KB]
    const int t = threadIdx.x;
    const int lane = t & 63;
    const int wave = t >> 6;          // 0..7
    const int wm = wave >> 2;         // 0..1 : M half (128 rows)
    const int wn = wave & 3;          // 0..3 : N quarter (64 cols)
    const int quad = lane >> 4, l16 = lane & 15;
    const long m0 = (long)m_idx * 256;
    const long n0 = (long)n_idx * 256;

    // folded LDS read bases (separable swizzle)
    const int aoff0 = l16 * 128 + ((quad ^ (l16 & 3)) << 4) + (((l16 >> 2) & 1) << 6);
    const int aoff1 = aoff0 ^ 64;                       // kk=1 flips byte-bit 6
    const int bex = (wn & 1) * 8192;
    const char* pAX0 = (const char*)&lds[0][wm][0] + aoff0;
    const char* pAX1 = (const char*)&lds[0][wm][0] + aoff1;
    const char* pAY0 = (const char*)&lds[1][wm][0] + aoff0;
    const char* pAY1 = (const char*)&lds[1][wm][0] + aoff1;
    const char* pBX0 = (const char*)&lds[0][2 + (wn >> 1)][0] + aoff0 + bex;
    const char* pBX1 = (const char*)&lds[0][2 + (wn >> 1)][0] + aoff1 + bex;
    const char* pBY0 = (const char*)&lds[1][2 + (wn >> 1)][0] + aoff0 + bex;
    const char* pBY1 = (const char*)&lds[1][2 + (wn >> 1)][0] + aoff1 + bex;

    // staging: chunk ck = wave*2+jj covers 8 rows (1KB); global 16B-slot
    // pre-swizzled g=(lane&7)^((lane>>3)&7) so swizzled read finds slot s^(row&7).
    const int gslot = (((lane & 7) ^ ((lane >> 3) & 7)) << 3);
    const int lane_row = lane >> 3;
    const long lane_go = (long)lane_row * K + gslot;

    auto stage = [&](u16* sreg, const u16* G, long rbase, long rmax, int kt, bool cl) {
        #pragma unroll
        for (int jj = 0; jj < 2; ++jj) {
            const int ck = wave * 2 + jj;
            const u16* gp;
            if (!cl) {
                gp = G + (rbase + ck * 8) * (long)K + ((long)kt << 6) + lane_go;
            } else {
                long r = rbase + ck * 8 + lane_row;
                if (r > rmax) r = rmax;      // tail clamp, masked at C store
                gp = G + r * (long)K + ((long)kt << 6) + gslot;
            }
            __builtin_amdgcn_global_load_lds(
                (__attribute__((address_space(1))) void*)(void*)gp,
                (__attribute__((address_space(3))) void*)((char*)sreg + ck * 1024),
                16, 0, 0);
        }
    };

    f32x4 acc[8][4];
    const f32x4 z4 = {0.f, 0.f, 0.f, 0.f};
    #pragma unroll
    for (int mi = 0; mi < 8; ++mi)
        #pragma unroll
        for (int ni = 0; ni < 4; ++ni)
            acc[mi][ni] = z4;
    frag8 av[4][2];
    frag8 bv[2][2][2];

    const int ntk = K >> 6;          // K multiple of 128 -> ntk even
    const int niter = ntk >> 1;
    const long MM = (long)M - 1, NMX = (long)N - 1;
    const bool aclamp = (m0 + 255) > MM;     // block-uniform

    stage(&lds[0][2][0], BT, n0,       NMX, 0, false);
    stage(&lds[0][3][0], BT, n0 + 128, NMX, 0, false);
    stage(&lds[0][0][0], A,  m0,       MM,  0, aclamp);
    stage(&lds[0][1][0], A,  m0 + 128, MM,  0, aclamp);
    stage(&lds[1][2][0], BT, n0,       NMX, 1, false);
    stage(&lds[1][3][0], BT, n0 + 128, NMX, 1, false);
    asm volatile("s_waitcnt vmcnt(4)" ::: "memory");   // tile0's 8 loads landed
    __builtin_amdgcn_s_barrier();

    for (int it = 0; it < niter; ++it) {
        const int t1k = 2 * it + 1;
        int t2k = 2 * it + 2; if (t2k > ntk - 1) t2k = ntk - 1;
        int t3k = 2 * it + 3; if (t3k > ntk - 1) t3k = ntk - 1;

        QPHASE(pAX0, pAX1, pBX0, pBX1, 0, 0, 1,  0, 0, &lds[1][0][0], A,  m0,       MM,  aclamp, t1k);
        QPHASE(pAX0, pAX1, pBX0, pBX1, 0, 1, 0,  1, 0, &lds[1][1][0], A,  m0 + 128, MM,  aclamp, t1k);
        QPHASE(pAX0, pAX1, pBX0, pBX1, 1, 0, 1, -1, 0, &lds[0][2][0], BT, n0,       NMX, false,  t2k);
        QPHASE(pAX0, pAX1, pBX0, pBX1, 1, 1, 0, -1, 1, &lds[0][3][0], BT, n0 + 128, NMX, false,  t2k);
        QPHASE(pAY0, pAY1, pBY0, pBY1, 0, 0, 1,  0, 0, &lds[0][0][0], A,  m0,       MM,  aclamp, t2k);
        QPHASE(pAY0, pAY1, pBY0, pBY1, 0, 1, 0,  1, 0, &lds[0][1][0], A,  m0 + 128, MM,  aclamp, t2k);
        QPHASE(pAY0, pAY1, pBY0, pBY1, 1, 0, 1, -1, 0, &lds[1][2][0], BT, n0,       NMX, false,  t3k);
        QPHASE(pAY0, pAY1, pBY0, pBY1, 1, 1, 0, -1, 1, &lds[1][3][0], BT, n0 + 128, NMX, false,  t3k);
    }
    asm volatile("s_waitcnt vmcnt(0)" ::: "memory");   // drain leftover stages

    #pragma unroll
    for (int mi = 0; mi < 8; ++mi) {
        #pragma unroll
        for (int r = 0; r < 4; ++r) {
            long row = m0 + wm * 128 + mi * 16 + quad * 4 + r;   // C/D: row = quad*4+reg
            if (row < M) {
                #pragma unroll
                for (int ni = 0; ni < 4; ++ni) {
                    long col = n0 + wn * 64 + ni * 16 + l16;     // C/D: col = lane&15
                    float v = acc[mi][ni][r] + bf2f(bias[col]);
                    C[row * (long)N + col] = f2bf(eluf(v));
                }
            }
        }
    }
}

// C[M,64] fp32 = A[M,K] @ BT[64,K]^T + bias (no ELU). M-tile 256, N=64, K mult of 32.
// Fused epilogue: if emit, also write xin = bf16(elu(v)) and nbr = 0 (next layer).
__global__ __launch_bounds__(256)
void gemm_bt_f32(const u16* __restrict__ A, const u16* __restrict__ BT,
                 const u16* __restrict__ bias, float* __restrict__ C,
                 u16* __restrict__ xinw, float* __restrict__ nbrw, int emit,
                 int M, int K) {
    __shared__ __align__(16) u16 sA[256 * 32];
    __shared__ __align__(16) u16 sB[64 * 32];
    const int t = threadIdx.x;
    const int lane = t & 63;
    const int wave = t >> 6;
    const int quad = lane >> 4, l16 = lane & 15;
    const long m0 = (long)blockIdx.x * 256;

    f32x4 acc[4][4];
    const f32x4 z4 = {0.f, 0.f, 0.f, 0.f};
    #pragma unroll
    for (int mi = 0; mi < 4; ++mi)
        #pragma unroll
        for (int ni = 0; ni < 4; ++ni)
            acc[mi][ni] = z4;

    for (int k0 = 0; k0 < K; k0 += 32) {
        #pragma unroll
        for (int j = 0; j < 4; ++j) {
            int c = t + 256 * j;
            long r = m0 + (c >> 2);
            if (r > (long)M - 1) r = (long)M - 1;
            const u16* gp = A + r * (long)K + k0 + (c & 3) * 8;
            __builtin_amdgcn_global_load_lds(
                (__attribute__((address_space(1))) void*)(void*)gp,
                (__attribute__((address_space(3))) void*)((char*)sA + wave * 1024 + j * 4096),
                16, 0, 0);
        }
        {
            int c = t;
            const u16* gp = BT + (long)(c >> 2) * K + k0 + (c & 3) * 8;
            __builtin_amdgcn_global_load_lds(
                (__attribute__((address_space(1))) void*)(void*)gp,
                (__attribute__((address_space(3))) void*)((char*)sB + wave * 1024),
                16, 0, 0);
        }
        __syncthreads();
        frag8 af[4], bfv[4];
        #pragma unroll
        for (int mi = 0; mi < 4; ++mi)
            af[mi] = *(const frag8*)(sA + (wave * 64 + mi * 16 + l16) * 32 + quad * 8);
        #pragma unroll
        for (int ni = 0; ni < 4; ++ni)
            bfv[ni] = *(const frag8*)(sB + (ni * 16 + l16) * 32 + quad * 8);
        #pragma unroll
        for (int mi = 0; mi < 4; ++mi)
            #pragma unroll
            for (int ni = 0; ni < 4; ++ni)
                acc[mi][ni] = __builtin_amdgcn_mfma_f32_16x16x32_bf16(af[mi], bfv[ni], acc[mi][ni], 0, 0, 0);
        __syncthreads();
    }

    #pragma unroll
    for (int mi = 0; mi < 4; ++mi) {
        #pragma unroll
        for (int r = 0; r < 4; ++r) {
            long row = m0 + wave * 64 + mi * 16 + quad * 4 + r;
            if (row < M) {
                #pragma unroll
                for (int ni = 0; ni < 4; ++ni) {
                    int col = ni * 16 + l16;
                    float v = acc[mi][ni][r] + bf2f(bias[col]);
                    C[row * 64 + col] = v;
                    if (emit) {
                        xinw[row * 64 + col] = f2bf(eluf(v));
                        nbrw[row * 64 + col] = 0.f;
                    }
                }
            }
        }
    }
}

// msg[e,o] = sum_i x[src[e],i] * we[e, i*64+o]; atomicAdd into agg[dst[e],o]
__global__ void nnconv_msg(const u16* __restrict__ we, const u16* __restrict__ x,
                           const int* __restrict__ src, const int* __restrict__ dst,
                           float* __restrict__ agg, int ce) {
    long idx = (long)blockIdx.x * 256 + threadIdx.x;
    if (idx >= (long)ce * 64) return;
    int o = (int)(idx & 63);
    long e = idx >> 6;
    const u16* wr = we + e * 1024;
    const u16* xr = x + (long)src[e] * 16;
    float v = 0.f;
    #pragma unroll
    for (int i = 0; i < 16; ++i)
        v += bf2f(xr[i]) * bf2f(wr[i * 64 + o]);
    atomicAdd(&agg[(long)dst[e] * 64 + o], v);
}

// ---- fused: x_cur = x@root_w + root_b + agg (in-place on agg=emb0);
// ALSO emit xin = bf16(elu(x_cur)) and nbr = 0 for GIN layer 0 ----
__global__ void add_root_fused(const u16* __restrict__ x, const u16* __restrict__ rw,
                               const u16* __restrict__ rb, float* __restrict__ xcur,
                               u16* __restrict__ xin, float* __restrict__ nbr) {
    long idx = (long)blockIdx.x * 256 + threadIdx.x;
    if (idx >= (long)NN * 64) return;
    int d = (int)(idx & 63);
    long n = idx >> 6;
    float v = bf2f(rb[d]);
    #pragma unroll
    for (int i = 0; i < 16; ++i)
        v += bf2f(x[n * 16 + i]) * bf2f(rw[i * 64 + d]);
    float total = xcur[idx] + v;
    xcur[idx] = total;
    xin[idx] = f2bf(eluf(total));
    nbr[idx] = 0.f;
}

__global__ void gin_scatter(const u16* __restrict__ xin, const int* __restrict__ src,
                            const int* __restrict__ dst, float* __restrict__ nbr) {
    long idx = (long)blockIdx.x * 256 + threadIdx.x;
    if (idx >= (long)EE * 64) return;
    int d = (int)(idx & 63);
    long e = idx >> 6;
    atomicAdd(&nbr[(long)dst[e] * 64 + d], bf2f(xin[(long)src[e] * 64 + d]));
}

// out[n,d,l] = emb_l[n*64+d] -- one float4 per (n,d), fully coalesced
__global__ void write_out(const float* __restrict__ e0, const float* __restrict__ e1,
                          const float* __restrict__ e2, const float* __restrict__ e3,
                          float* __restrict__ out) {
    long idx = (long)blockIdx.x * 256 + threadIdx.x;
    if (idx >= (long)NN * 64) return;
    float4 v = {e0[idx], e1[idx], e2[idx], e3[idx]};
    *(float4*)(out + idx * 4) = v;
}

extern "C" void kernel_launch(void* const* d_in, const int* in_sizes, int n_in,
                              void* d_out, int out_size, void* d_ws, size_t ws_size,
                              hipStream_t stream) {
    (void)in_sizes; (void)n_in; (void)out_size;
    const void* eidx = d_in[1];
    float* out = (float*)d_out;   // reference output dtype = float32

    char* ws = (char*)d_ws;
    size_t off = 0;
    auto alloc = [&](size_t bytes) {
        char* p = ws + off;
        off += (bytes + 255) & ~(size_t)255;
        return p;
    };
    // ---- persistent ----
    int* src32 = (int*)alloc((size_t)EE * 4);
    int* dst32 = (int*)alloc((size_t)EE * 4);
    int* flag  = (int*)alloc(256);
    int* cnt   = (int*)alloc(256);
    const int cv_idx[16] = {0, 2, 3, 4, 5, 6, 7, 8, 9, 10, 11, 12, 13, 14, 15, 16};
    const long cv_n[16]  = {800000, 3200000, 4096, 256, 262144, 1024, 1048576, 1024,
                            1024, 64, 49152, 768, 196608, 768, 49152, 192};
    u16* cv[16];
    for (int i = 0; i < 16; ++i) cv[i] = (u16*)alloc((size_t)cv_n[i] * 2);
    u16 *xc = cv[0], *eac = cv[1], *w1c = cv[2], *b1c = cv[3], *w2c = cv[4], *b2c = cv[5],
        *w3c = cv[6], *b3c = cv[7], *rwc = cv[8], *rbc = cv[9],
        *g1c = cv[10], *gb1c = cv[11], *g2c = cv[12], *gb2c = cv[13], *g3c = cv[14], *gb3c = cv[15];
    u16* w2t = (u16*)alloc((size_t)1024 * 256 * 2);
    u16* w3t = (u16*)alloc((size_t)1024 * 1024 * 2);
    u16* g1t = (u16*)alloc((size_t)3 * 256 * 64 * 2);
    u16* g2t = (u16*)alloc((size_t)3 * 256 * 256 * 2);
    u16* g3t = (u16*)alloc((size_t)3 * 64 * 256 * 2);
    u16* attr32 = (u16*)alloc((size_t)EE * 32 * 2);   // padded edge_attr, K=32
    u16* w1t32  = (u16*)alloc((size_t)256 * 32 * 2);  // padded w1^T [256][32]
    // per-layer node embeddings, fp32 [N,64]; emb[0] doubles as agg/x_cur
    float* emb[4];
    for (int l = 0; l < 4; ++l) emb[l] = (float*)alloc((size_t)NN * 64 * 4);
    float* agg = emb[0];
    char* scratch = (char*)alloc(0);
    size_t avail = (ws_size > off + 4096) ? (ws_size - off - 4096) : 0;

    // ---- NNConv edge-chunk plan: h1c (512 B/e) + h2c (2048 B/e) + wec (2048 B/e) ----
    // Round-exact grids (R18-confirmed): full chunks of 32768 (grid 512 = 2 rounds,
    // num_m 128 = 8x16 exact). Tail merged into the last chunk when buffers allow.
    long CEBUF;                 // buffer sizing (max chunk)
    long plan[8]; int nplan;
    if (avail >= 36160L * 4608) {
        CEBUF = 36160;          // {5 x 32768, 36160} -> 24 dispatches, 13 L3-rounds
        nplan = 6;
        for (int i = 0; i < 5; ++i) plan[i] = 32768;
        plan[5] = 36160;
    } else if (avail >= 32768L * 4608) {
        CEBUF = 32768;          // {6 x 32768, 3392}  (R18 plan)
        nplan = 7;
        for (int i = 0; i < 6; ++i) plan[i] = 32768;
        plan[6] = 3392;
    } else {                    // fallback: dynamic uniform chunks
        CEBUF = (long)(avail / 4608) & ~255L;
        if (CEBUF < 256) CEBUF = 256;
        nplan = 0;
        long rem = EE;
        while (rem > 0 && nplan < 8) {
            long c = rem < CEBUF ? rem : CEBUF;
            plan[nplan++] = c;
            rem -= c;
        }
    }
    u16* h1c = (u16*)scratch;
    u16* h2c = (u16*)(scratch + (size_t)CEBUF * 512);
    u16* wec = (u16*)(scratch + (size_t)CEBUF * 2560);

    // ---- GIN node-chunk: nbr+xin fixed (19.2MB) + hg1/hg2 1024 B/node ----
    long gin_fixed = (long)NN * 64 * 4 + (long)NN * 64 * 2;
    long gin_avail = (long)avail - gin_fixed;
    if (gin_avail < 0) gin_avail = 0;
    long CN = (gin_avail / 1024) & ~255L;
    if (CN < 256) CN = 256;
    if (CN > 50176) CN = 50176;
    float* nbr = (float*)scratch;
    u16* xin   = (u16*)(scratch + (size_t)NN * 64 * 4);
    u16* hg1   = (u16*)(scratch + gin_fixed);
    u16* hg2   = hg1 + (size_t)CN * 256;

    auto cdiv = [](long a, long b) { return (unsigned)((a + b - 1) / b); };

    // dtype probe on x, then normalize all float inputs to bf16 (ONE batched launch)
    hipMemsetAsync(cnt, 0, 4, stream);
    probe_f32<<<1, 256, 0, stream>>>((const u16*)d_in[0], cnt);
    {
        CvtPtrs cp;
        for (int i = 0; i < 16; ++i) { cp.src[i] = d_in[cv_idx[i]]; cp.dst[i] = cv[i]; }
        long total = 0;
        for (int i = 0; i < 16; ++i) total += cv_n[i];
        cvt_all<<<cdiv(total, 256), 256, 0, stream>>>(cp, cnt);
    }

    // edge_index conversion (layout-robust)
    hipMemsetAsync(flag, 0, 4, stream);
    detect_idx64<<<cdiv(EE, 256), 256, 0, stream>>>((const unsigned long long*)eidx, flag);
    convert_idx<<<cdiv(EE, 256), 256, 0, stream>>>(eidx, flag, src32, dst32);

    // weight transposes [K,N] -> [N,K] (ONE batched launch; order matches TK/TN tables)
    {
        TransPtrs tp;
        tp.in[0] = w2c;  tp.out[0] = w2t;
        tp.in[1] = w3c;  tp.out[1] = w3t;
        for (int l = 0; l < 3; ++l) {
            tp.in[2 + 3 * l] = g1c + l * 64 * 256;   tp.out[2 + 3 * l] = g1t + l * 256 * 64;
            tp.in[3 + 3 * l] = g2c + l * 256 * 256;  tp.out[3 + 3 * l] = g2t + l * 256 * 256;
            tp.in[4 + 3 * l] = g3c + l * 256 * 64;   tp.out[4 + 3 * l] = g3t + l * 64 * 256;
        }
        long total = 262144 + 1048576 + 3 * (16384 + 65536 + 16384);
        transpose_all<<<cdiv(total, 256), 256, 0, stream>>>(tp);
    }
    // pad attr K=16 -> K=32 (once) and w1 -> padded BT [256][32]
    pad_attr<<<cdiv((long)EE * 32, 256), 256, 0, stream>>>(eac, attr32);
    pad_w1t<<<cdiv(256 * 32, 256), 256, 0, stream>>>(w1c, w1t32);

    // ---- NNConv (edge-chunked) ----
    hipMemsetAsync(agg, 0, (size_t)NN * 64 * 4, stream);
    {
        long e0 = 0;
        for (int c = 0; c < nplan; ++c) {
            int ce = (int)plan[c];
            int mpx  = cdiv(cdiv(ce, 128), 8);
            int mpx2 = cdiv(cdiv(ce, 256), 8);
            gemm_bt_bias_elu<<<8 * mpx * 2, 256, 0, stream>>>(attr32 + e0 * 32, w1t32, b1c, h1c, ce, 32, 256, mpx, 1);
            gemm256p<<<8 * mpx2 * 4, 512, 0, stream>>>(h1c, w2t, b2c, h2c, ce, 256, 1024, mpx2, 2);
            gemm256p<<<8 * mpx2 * 4, 512, 0, stream>>>(h2c, w3t, b3c, wec, ce, 1024, 1024, mpx2, 2);
            nnconv_msg<<<cdiv((long)ce * 64, 256), 256, 0, stream>>>(wec, xc, src32 + e0, dst32 + e0, agg, ce);
            e0 += ce;
        }
    }
    // fused: emb0 = x@rw + b + agg; xin = bf16(elu(emb0)); nbr = 0  (layer-0 prep)
    add_root_fused<<<cdiv((long)NN * 64, 256), 256, 0, stream>>>(xc, rwc, rbc, agg, xin, nbr);

    // ---- 3x GINConv (node-chunked MLP; combine fused into g1, elu fused into g3) ----
    for (int l = 0; l < 3; ++l) {
        gin_scatter<<<cdiv((long)EE * 64, 256), 256, 0, stream>>>(xin, src32, dst32, nbr);
        for (long n0 = 0; n0 < NN; n0 += CN) {
            int cn = (int)((NN - n0 < CN) ? (NN - n0) : CN);
            int mpx = cdiv(cdiv(cn, 128), 8);
            gemm_bt_g1<<<8 * mpx * 2, 256, 0, stream>>>(xin + n0 * 64, nbr + n0 * 64,
                                                        g1t + l * 256 * 64, gb1c + l * 256, hg1, cn, 64, 256, mpx, 1);
            gemm_bt_bias_elu<<<8 * mpx * 2, 256, 0, stream>>>(hg1, g2t + l * 256 * 256, gb2c + l * 256, hg2, cn, 256, 256, mpx, 1);
            gemm_bt_f32<<<cdiv(cn, 256), 256, 0, stream>>>(hg2, g3t + l * 64 * 256, gb3c + l * 64,
                                                           emb[l + 1] + n0 * 64, xin + n0 * 64, nbr + n0 * 64,
                                                           (l < 2) ? 1 : 0, cn, 256);
        }
    }
    write_out<<<cdiv((long)NN * 64, 256), 256, 0, stream>>>(emb[0], emb[1], emb[2], emb[3], out);
}